// Round 2
// baseline (407.250 us; speedup 1.0000x reference)
//
#include <hip/hip_runtime.h>
#include <cstdio>

// ---------------- problem constants ----------------
constexpr int T  = 4096;       // B*S tokens
constexpr int D  = 1024;       // n_embed
constexpr int M  = 1408;       // n_moe_mlp
constexpr int E  = 8;          // experts

constexpr int TM = 128;        // token-rows per tile
constexpr int TN = 128;        // output cols per tile
constexpr int BK = 64;         // K-step
constexpr int RCAP = T * 2 + E * TM;  // 9216 padded row capacity
constexpr int MT_MAX = T / TM; // 32 row-tiles max per expert
constexpr int NT_UP = M / TN;  // 11
constexpr int NT_DN = D / TN;  // 8

constexpr int CSTR = 64;       // per-expert counter stride in ints (256 B)
constexpr int TOKB = 16;       // tokens per router block (16 -> 256 router blocks)
constexpr int RTB  = T / TOKB; // 256 router blocks
constexpr int TP_PER_W = (M / 32) * (D / 32) * E;  // 11264 transpose blocks per weight
constexpr int PREP_GRID = RTB + 3 * TP_PER_W;      // 34048

typedef _Float16 half8 __attribute__((ext_vector_type(8)));
typedef _Float16 half4 __attribute__((ext_vector_type(4)));
typedef float    floatx4 __attribute__((ext_vector_type(4)));

// ---------------- ws layout (bytes) ----------------
constexpr size_t OFF_COUNTS = 0;                               // E*CSTR ints
constexpr size_t OFF_BASE   = (size_t)E * CSTR * 4;            // (legacy, unused)
constexpr size_t OFF_PC     = OFF_BASE + 64;
constexpr size_t OFF_TOTAL  = OFF_PC + 64;
constexpr size_t OFF_T2E    = OFF_TOTAL + 64;                  // 2T ints
constexpr size_t OFF_T2POS  = OFF_T2E   + (size_t)2 * T * 4;
constexpr size_t OFF_T2P    = OFF_T2POS + (size_t)2 * T * 4;
constexpr size_t OFF_TLIST  = OFF_T2P   + (size_t)2 * T * 4;   // E*T ints
constexpr size_t OFF_XG     = OFF_TLIST + (size_t)E * T * 4;   // RCAP x D fp16 (reused as Yp)
constexpr size_t OFF_HID    = OFF_XG  + (size_t)RCAP * D * 2;  // RCAP x M fp16
constexpr size_t OFF_WGT    = OFF_HID + (size_t)RCAP * M * 2;  // E x M x D fp16
constexpr size_t OFF_WUT    = OFF_WGT + (size_t)E * M * D * 2;
constexpr size_t OFF_WDT    = OFF_WUT + (size_t)E * M * D * 2; // E x D x M fp16
constexpr size_t WS_NEED    = OFF_WDT + (size_t)E * D * M * 2;

// async global->LDS, 16B per lane. LDS dest = wave-uniform base + lane*16.
__device__ __forceinline__ void gl_lds16(const void* g, void* l) {
  __builtin_amdgcn_global_load_lds(
      (const __attribute__((address_space(1))) unsigned int*)g,
      (__attribute__((address_space(3))) unsigned int*)l, 16, 0, 0);
}

// 8-expert padded prefix via uniform scalar loads.
__device__ __forceinline__ void expert_base_pc(const int* __restrict__ counts,
                                               int e, int& base_e, int& pc_e) {
  int b = 0; base_e = 0; pc_e = 0;
  #pragma unroll
  for (int ee = 0; ee < E; ++ee) {
    int c = counts[ee * CSTR];
    int p = (c + TM - 1) / TM * TM;
    if (ee == e) { base_e = b; pc_e = p; }
    b += p;
  }
}

// ---------------- fused prep: router blocks + weight-transpose blocks ----------
__global__ __launch_bounds__(256) void k_prep(
    const float* __restrict__ x, const float* __restrict__ wgate,
    const float* __restrict__ w_g, const float* __restrict__ w_u,
    const float* __restrict__ w_d,
    _Float16* __restrict__ wgT, _Float16* __restrict__ wuT, _Float16* __restrict__ wdT,
    int* __restrict__ counts, int* __restrict__ tlist,
    int* __restrict__ t2e, int* __restrict__ t2pos, float* __restrict__ t2p) {
  __shared__ float tile[32][33];
  __shared__ int   s_cnt[E];
  __shared__ int   s_base[E];
  __shared__ int   s_e[2 * TOKB];
  __shared__ int   s_pos[2 * TOKB];
  __shared__ float s_p[2 * TOKB];
  int bid = blockIdx.x;

  if (bid < RTB) {
    // ---- router for tokens [bid*TOKB, +TOKB) ----
    int wv = threadIdx.x >> 6, lane = threadIdx.x & 63;
    if (threadIdx.x < E) s_cnt[threadIdx.x] = 0;
    __syncthreads();
    for (int j = 0; j < TOKB / 4; ++j) {
      int tl = wv * (TOKB / 4) + j;
      int t  = bid * TOKB + tl;
      const float* xr = x + (size_t)t * D;
      float acc[E] = {0.f,0.f,0.f,0.f,0.f,0.f,0.f,0.f};
      #pragma unroll
      for (int i = 0; i < D / 64; ++i) {
        int d = i * 64 + lane;
        float xv = xr[d];
        const float4* wr2 = (const float4*)(wgate + (size_t)d * E);
        float4 w0 = wr2[0], w1 = wr2[1];
        acc[0] += xv * w0.x; acc[1] += xv * w0.y; acc[2] += xv * w0.z; acc[3] += xv * w0.w;
        acc[4] += xv * w1.x; acc[5] += xv * w1.y; acc[6] += xv * w1.z; acc[7] += xv * w1.w;
      }
      #pragma unroll
      for (int e = 0; e < E; ++e) {
        #pragma unroll
        for (int off = 32; off; off >>= 1) acc[e] += __shfl_xor(acc[e], off, 64);
      }
      if (lane == 0) {
        int i0 = 0; float s0 = acc[0];
        #pragma unroll
        for (int e = 1; e < E; ++e) if (acc[e] > s0) { s0 = acc[e]; i0 = e; }
        int i1 = -1; float s1 = -1e30f;
        #pragma unroll
        for (int e = 0; e < E; ++e) if (e != i0 && acc[e] > s1) { s1 = acc[e]; i1 = e; }
        float p0 = 1.f / (1.f + expf(s1 - s0));
        float p1 = 1.f - p0;
        int q0 = atomicAdd(&s_cnt[i0], 1);
        int q1 = atomicAdd(&s_cnt[i1], 1);
        s_e[2 * tl]     = i0; s_pos[2 * tl]     = q0; s_p[2 * tl]     = p0;
        s_e[2 * tl + 1] = i1; s_pos[2 * tl + 1] = q1; s_p[2 * tl + 1] = p1;
      }
    }
    __syncthreads();
    if (threadIdx.x < E)
      s_base[threadIdx.x] = atomicAdd(&counts[threadIdx.x * CSTR], s_cnt[threadIdx.x]);
    __syncthreads();
    if (threadIdx.x < 2 * TOKB) {
      int sl = threadIdx.x;
      int e = s_e[sl];
      int pos = s_base[e] + s_pos[sl];
      int t = bid * TOKB + (sl >> 1);
      tlist[e * T + pos] = t;
      t2e[2 * t + (sl & 1)]   = e;
      t2pos[2 * t + (sl & 1)] = pos;
      t2p[2 * t + (sl & 1)]   = s_p[sl];
    }
    return;
  }

  // ---- transpose-convert [E][R][C] f32 -> [E][C][R] f16 ----
  int i = bid - RTB;
  int which = i / TP_PER_W;
  int j = i - which * TP_PER_W;
  const float* src; _Float16* dst; int Rr, Cc;
  if (which == 0)      { src = w_g; dst = wgT; Rr = D; Cc = M; }
  else if (which == 1) { src = w_u; dst = wuT; Rr = D; Cc = M; }
  else                 { src = w_d; dst = wdT; Rr = M; Cc = D; }
  int ctn = Cc / 32, rtn = Rr / 32;
  int e   = j / (ctn * rtn);
  int rem = j - e * (ctn * rtn);
  int rt = rem / ctn, ct = rem - rt * ctn;
  int tr  = threadIdx.x >> 3;
  int tc4 = (threadIdx.x & 7) * 4;
  const float* s = src + ((size_t)e * Rr + rt * 32 + tr) * Cc + ct * 32 + tc4;
  float4 v = *(const float4*)s;
  tile[tr][tc4 + 0] = v.x; tile[tr][tc4 + 1] = v.y;
  tile[tr][tc4 + 2] = v.z; tile[tr][tc4 + 3] = v.w;
  __syncthreads();
  union { _Float16 h[4]; ushort4 u; } o;
  #pragma unroll
  for (int q = 0; q < 4; ++q) o.h[q] = (_Float16)tile[tc4 + q][tr];
  *(ushort4*)(dst + ((size_t)e * Cc + ct * 32 + tr) * Rr + rt * 32 + tc4) = o.u;
}

// ---------------- gather tokens -> fp16, zero pad rows ----------------
__global__ __launch_bounds__(256) void k_gather(
    const float* __restrict__ x, const int* __restrict__ counts,
    const int* __restrict__ tlist, _Float16* __restrict__ Xg) {
  int r = blockIdx.x;
  int b = 0, e = -1, local = 0, cnt = 0;
  #pragma unroll
  for (int ee = 0; ee < E; ++ee) {
    int c = counts[ee * CSTR];
    int p = (c + TM - 1) / TM * TM;
    if (e < 0 && r < b + p) { e = ee; local = r - b; cnt = c; }
    b += p;
  }
  if (e < 0) return;
  int d = threadIdx.x * 4;
  union { _Float16 h[4]; ushort4 u; } o;
  if (local < cnt) {
    int t = tlist[e * T + local];
    float4 v = *(const float4*)(x + (size_t)t * D + d);
    o.h[0] = (_Float16)v.x; o.h[1] = (_Float16)v.y;
    o.h[2] = (_Float16)v.z; o.h[3] = (_Float16)v.w;
  } else {
    o.h[0] = (_Float16)0.f; o.h[1] = (_Float16)0.f;
    o.h[2] = (_Float16)0.f; o.h[3] = (_Float16)0.f;
  }
  *(ushort4*)(Xg + (size_t)r * D + d) = o.u;
}

// ---------------- fused gate+up grouped GEMM + SiLU (BK=64, XOR-swizzled LDS) --
// Swizzle (rule #21, both-sides): global_load_lds writes LINEARLY, so the
// permutation is applied on the per-lane GLOBAL source (chunk ^= row&7) and
// the ds_read side applies the same XOR. 16 lanes/quad now spread over all
// 32 banks (2-way = free) instead of a 16-way pileup at 128B row stride.
__global__ __launch_bounds__(256, 3) void k_upgate(
    const _Float16* __restrict__ Xg, const _Float16* __restrict__ wgT,
    const _Float16* __restrict__ wuT, _Float16* __restrict__ Hid,
    const int* __restrict__ counts) {
  int lin = blockIdx.x;
  int e = lin & 7;
  int r = lin >> 3;
  int nt = r % NT_UP;
  int mt = r / NT_UP;
  int base_e, pc_e;
  expert_base_pc(counts, e, base_e, pc_e);
  if (mt * TM >= pc_e) return;
  int row0 = base_e + mt * TM;
  int n0 = nt * TN;
  __shared__ _Float16 As[TM * BK];   // 16 KB
  __shared__ _Float16 Bg[TN * BK];   // 16 KB
  __shared__ _Float16 Bu[TN * BK];   // 16 KB
  int tid = threadIdx.x;
  int w = tid >> 6, lane = tid & 63;
  int lrow = lane & 15, quad = lane >> 4;
  int wr = w >> 1, wc = w & 1;
  int sr = lane >> 3;                      // staging row within 8-row group
  int sc = (((lane & 7) ^ sr) & 7) * 8;    // pre-swizzled global k-chunk (halves)

  const _Float16* wg_e = wgT + (size_t)e * M * D;
  const _Float16* wu_e = wuT + (size_t)e * M * D;
  const _Float16* pA[4]; const _Float16* pG[4]; const _Float16* pU[4];
  char* lA[4]; char* lG[4]; char* lU[4];
  #pragma unroll
  for (int rr = 0; rr < 4; ++rr) {
    int grow = w * 32 + rr * 8 + sr;
    pA[rr] = Xg   + (size_t)(row0 + grow) * D + sc;
    pG[rr] = wg_e + (size_t)(n0   + grow) * D + sc;
    pU[rr] = wu_e + (size_t)(n0   + grow) * D + sc;
    lA[rr] = (char*)As + (w * 4 + rr) * 1024;
    lG[rr] = (char*)Bg + (w * 4 + rr) * 1024;
    lU[rr] = (char*)Bu + (w * 4 + rr) * 1024;
  }

  // swizzled read chunk indices (halves offset within a 64-half row)
  int swA = lrow & 7;  // row&7 for A rows (wr*64+i*16+lrow)
  int swB = lrow & 7;  // row&7 for B rows (wc*64+c*16+lrow)

  floatx4 accg[4][4] = {};   // [c][i]
  floatx4 accu[4][4] = {};

  for (int k0 = 0; k0 < D; k0 += BK) {
    #pragma unroll
    for (int rr = 0; rr < 4; ++rr) {
      gl_lds16(pA[rr], lA[rr]);
      gl_lds16(pG[rr], lG[rr]);
      gl_lds16(pU[rr], lU[rr]);
      pA[rr] += BK; pG[rr] += BK; pU[rr] += BK;
    }
    __syncthreads();
    #pragma unroll
    for (int c2 = 0; c2 < 2; ++c2) {
      half8 af[4];
      #pragma unroll
      for (int i = 0; i < 4; ++i)
        af[i] = *(const half8*)&As[(wr * 64 + i * 16 + lrow) * BK +
                                   (((c2 * 4 + quad) ^ swA) * 8)];
      #pragma unroll
      for (int c = 0; c < 4; ++c) {
        int bo = (wc * 64 + c * 16 + lrow) * BK + (((c2 * 4 + quad) ^ swB) * 8);
        half8 bgc = *(const half8*)&Bg[bo];
        half8 buc = *(const half8*)&Bu[bo];
        #pragma unroll
        for (int i = 0; i < 4; ++i) {
          accg[c][i] = __builtin_amdgcn_mfma_f32_16x16x32_f16(af[i], bgc, accg[c][i], 0, 0, 0);
          accu[c][i] = __builtin_amdgcn_mfma_f32_16x16x32_f16(af[i], buc, accu[c][i], 0, 0, 0);
        }
      }
    }
    __syncthreads();
  }
  #pragma unroll
  for (int c = 0; c < 4; ++c) {
    int col = n0 + wc * 64 + c * 16 + lrow;
    #pragma unroll
    for (int i = 0; i < 4; ++i) {
      int rowb = row0 + wr * 64 + i * 16 + quad * 4;
      #pragma unroll
      for (int reg = 0; reg < 4; ++reg) {
        float g = accg[c][i][reg], u = accu[c][i][reg];
        Hid[(size_t)(rowb + reg) * M + col] = (_Float16)(g / (1.f + expf(-g)) * u);
      }
    }
  }
}

// ---------------- down grouped GEMM -> per-slot rows Yp (BK=64, swizzled) ----
__global__ __launch_bounds__(256, 3) void k_down(
    const _Float16* __restrict__ Hid, const _Float16* __restrict__ wdT,
    _Float16* __restrict__ Yp, const int* __restrict__ counts) {
  int lin = blockIdx.x;
  int e = lin & 7;
  int r = lin >> 3;
  int nt = r % NT_DN;
  int mt = r / NT_DN;
  int base_e, pc_e;
  expert_base_pc(counts, e, base_e, pc_e);
  if (mt * TM >= pc_e) return;
  int row0 = base_e + mt * TM;
  int d0 = nt * TN;
  __shared__ _Float16 As[TM * BK];   // 16 KB
  __shared__ _Float16 Bs[TN * BK];   // 16 KB
  int tid = threadIdx.x;
  int w = tid >> 6, lane = tid & 63;
  int lrow = lane & 15, quad = lane >> 4;
  int wr = w >> 1, wc = w & 1;
  int sr = lane >> 3;
  int sc = (((lane & 7) ^ sr) & 7) * 8;

  const _Float16* wd_e = wdT + (size_t)e * D * M;
  const _Float16* pA[4]; const _Float16* pB[4];
  char* lA[4]; char* lB[4];
  #pragma unroll
  for (int rr = 0; rr < 4; ++rr) {
    int grow = w * 32 + rr * 8 + sr;
    pA[rr] = Hid  + (size_t)(row0 + grow) * M + sc;
    pB[rr] = wd_e + (size_t)(d0   + grow) * M + sc;
    lA[rr] = (char*)As + (w * 4 + rr) * 1024;
    lB[rr] = (char*)Bs + (w * 4 + rr) * 1024;
  }

  int sw = lrow & 7;

  floatx4 acc[4][4] = {};

  for (int k0 = 0; k0 < M; k0 += BK) {
    #pragma unroll
    for (int rr = 0; rr < 4; ++rr) {
      gl_lds16(pA[rr], lA[rr]);
      gl_lds16(pB[rr], lB[rr]);
      pA[rr] += BK; pB[rr] += BK;
    }
    __syncthreads();
    #pragma unroll
    for (int c2 = 0; c2 < 2; ++c2) {
      half8 af[4];
      #pragma unroll
      for (int i = 0; i < 4; ++i)
        af[i] = *(const half8*)&As[(wr * 64 + i * 16 + lrow) * BK +
                                   (((c2 * 4 + quad) ^ sw) * 8)];
      #pragma unroll
      for (int c = 0; c < 4; ++c) {
        half8 bc = *(const half8*)&Bs[(wc * 64 + c * 16 + lrow) * BK +
                                      (((c2 * 4 + quad) ^ sw) * 8)];
        #pragma unroll
        for (int i = 0; i < 4; ++i)
          acc[c][i] = __builtin_amdgcn_mfma_f32_16x16x32_f16(af[i], bc, acc[c][i], 0, 0, 0);
      }
    }
    __syncthreads();
  }
  #pragma unroll
  for (int c = 0; c < 4; ++c) {
    int col = d0 + wc * 64 + c * 16 + lrow;
    #pragma unroll
    for (int i = 0; i < 4; ++i) {
      int rowb = row0 + wr * 64 + i * 16 + quad * 4;
      #pragma unroll
      for (int reg = 0; reg < 4; ++reg)
        Yp[(size_t)(rowb + reg) * D + col] = (_Float16)acc[c][i][reg];
    }
  }
}

// ---------------- combine: y[t] = p0*Yp[r0] + p1*Yp[r1] ----------------
__global__ __launch_bounds__(256) void k_combine(
    const _Float16* __restrict__ Yp, const int* __restrict__ counts,
    const int* __restrict__ t2e, const int* __restrict__ t2pos,
    const float* __restrict__ t2p, float* __restrict__ out) {
  int t = blockIdx.x;
  int e0 = t2e[2 * t], e1 = t2e[2 * t + 1];
  int b = 0, b0 = 0, b1 = 0;
  #pragma unroll
  for (int ee = 0; ee < E; ++ee) {
    if (ee == e0) b0 = b;
    if (ee == e1) b1 = b;
    int c = counts[ee * CSTR];
    b += (c + TM - 1) / TM * TM;
  }
  int r0 = b0 + t2pos[2 * t];
  int r1 = b1 + t2pos[2 * t + 1];
  float p0 = t2p[2 * t], p1 = t2p[2 * t + 1];
  int d = threadIdx.x * 4;
  half4 h0 = *(const half4*)(Yp + (size_t)r0 * D + d);
  half4 h1 = *(const half4*)(Yp + (size_t)r1 * D + d);
  float4 o;
  o.x = p0 * (float)h0.x + p1 * (float)h1.x;
  o.y = p0 * (float)h0.y + p1 * (float)h1.y;
  o.z = p0 * (float)h0.z + p1 * (float)h1.z;
  o.w = p0 * (float)h0.w + p1 * (float)h1.w;
  *(float4*)(out + (size_t)t * D + d) = o;
}

// ---------------- launch ----------------
extern "C" void kernel_launch(void* const* d_in, const int* in_sizes, int n_in,
                              void* d_out, int out_size, void* d_ws, size_t ws_size,
                              hipStream_t stream) {
  const float* x     = (const float*)d_in[0];
  const float* wgate = (const float*)d_in[1];
  const float* w_g   = (const float*)d_in[2];
  const float* w_u   = (const float*)d_in[3];
  const float* w_d   = (const float*)d_in[4];
  float* out = (float*)d_out;
  char* ws = (char*)d_ws;

  if (ws_size < WS_NEED) {
    fprintf(stderr, "kernel_launch: ws_size=%zu < needed %zu\n", ws_size, WS_NEED);
    return;
  }

  int* counts = (int*)(ws + OFF_COUNTS);
  int* t2e    = (int*)(ws + OFF_T2E);
  int* t2pos  = (int*)(ws + OFF_T2POS);
  float* t2p  = (float*)(ws + OFF_T2P);
  int* tlist  = (int*)(ws + OFF_TLIST);
  _Float16* Xg  = (_Float16*)(ws + OFF_XG);   // later reused as Yp
  _Float16* Hid = (_Float16*)(ws + OFF_HID);
  _Float16* wgT = (_Float16*)(ws + OFF_WGT);
  _Float16* wuT = (_Float16*)(ws + OFF_WUT);
  _Float16* wdT = (_Float16*)(ws + OFF_WDT);

  hipMemsetAsync(counts, 0, (size_t)E * CSTR * 4, stream);

  k_prep<<<PREP_GRID, 256, 0, stream>>>(x, wgate, w_g, w_u, w_d,
                                        wgT, wuT, wdT,
                                        counts, tlist, t2e, t2pos, t2p);
  k_gather<<<RCAP, 256, 0, stream>>>(x, counts, tlist, Xg);
  k_upgate<<<E * MT_MAX * NT_UP, 256, 0, stream>>>(Xg, wgT, wuT, Hid, counts);
  _Float16* Yp = Xg;   // Xg dead; reuse as Yp
  k_down<<<E * MT_MAX * NT_DN, 256, 0, stream>>>(Hid, wdT, Yp, counts);
  k_combine<<<T, 256, 0, stream>>>(Yp, counts, t2e, t2pos, t2p, out);
}

// Round 4
// 332.125 us; speedup vs baseline: 1.2262x; 1.2262x over previous
//
#include <hip/hip_runtime.h>
#include <cstdio>

// ---------------- problem constants ----------------
constexpr int T  = 4096;       // B*S tokens
constexpr int D  = 1024;       // n_embed
constexpr int M  = 1408;       // n_moe_mlp
constexpr int E  = 8;          // experts

constexpr int TM = 128;        // token-rows per tile
constexpr int TN = 128;        // output cols per tile
constexpr int BK = 64;         // K-step
constexpr int RCAP = T * 2 + E * TM;  // 9216 padded row capacity
constexpr int MT_MAX = T / TM; // 32 row-tiles max per expert
constexpr int NT_UP = M / TN;  // 11
constexpr int NT_DN = D / TN;  // 8

constexpr int CSTR = 64;       // per-expert counter stride in ints (256 B)
constexpr int TOKB = 16;       // tokens per router block (16 -> 256 router blocks)
constexpr int RTB  = T / TOKB; // 256 router blocks
constexpr int TP_PER_W = (M / 32) * (D / 32) * E;  // 11264 transpose blocks per weight
constexpr int PREP_GRID = RTB + 3 * TP_PER_W;      // 34048

typedef _Float16 half8 __attribute__((ext_vector_type(8)));
typedef _Float16 half4 __attribute__((ext_vector_type(4)));
typedef float    floatx4 __attribute__((ext_vector_type(4)));

// ---------------- ws layout (bytes) ----------------
constexpr size_t OFF_COUNTS = 0;                               // E*CSTR ints
constexpr size_t OFF_BASE   = (size_t)E * CSTR * 4;            // (legacy, unused)
constexpr size_t OFF_PC     = OFF_BASE + 64;
constexpr size_t OFF_TOTAL  = OFF_PC + 64;
constexpr size_t OFF_T2E    = OFF_TOTAL + 64;                  // 2T ints
constexpr size_t OFF_T2POS  = OFF_T2E   + (size_t)2 * T * 4;
constexpr size_t OFF_T2P    = OFF_T2POS + (size_t)2 * T * 4;
constexpr size_t OFF_TLIST  = OFF_T2P   + (size_t)2 * T * 4;   // E*T ints
constexpr size_t OFF_XG     = OFF_TLIST + (size_t)E * T * 4;   // RCAP x D fp16 (reused as Yp)
constexpr size_t OFF_HID    = OFF_XG  + (size_t)RCAP * D * 2;  // RCAP x M fp16
constexpr size_t OFF_WGT    = OFF_HID + (size_t)RCAP * M * 2;  // E x M x D fp16
constexpr size_t OFF_WUT    = OFF_WGT + (size_t)E * M * D * 2;
constexpr size_t OFF_WDT    = OFF_WUT + (size_t)E * M * D * 2; // E x D x M fp16
constexpr size_t WS_NEED    = OFF_WDT + (size_t)E * D * M * 2;

// async global->LDS, 16B per lane. LDS dest = wave-uniform base + lane*16.
__device__ __forceinline__ void gl_lds16(const void* g, void* l) {
  __builtin_amdgcn_global_load_lds(
      (const __attribute__((address_space(1))) unsigned int*)g,
      (__attribute__((address_space(3))) unsigned int*)l, 16, 0, 0);
}

// 8-expert padded prefix via uniform scalar loads.
__device__ __forceinline__ void expert_base_pc(const int* __restrict__ counts,
                                               int e, int& base_e, int& pc_e) {
  int b = 0; base_e = 0; pc_e = 0;
  #pragma unroll
  for (int ee = 0; ee < E; ++ee) {
    int c = counts[ee * CSTR];
    int p = (c + TM - 1) / TM * TM;
    if (ee == e) { base_e = b; pc_e = p; }
    b += p;
  }
}

// ---------------- fused prep: router blocks + weight-transpose blocks ----------
__global__ __launch_bounds__(256) void k_prep(
    const float* __restrict__ x, const float* __restrict__ wgate,
    const float* __restrict__ w_g, const float* __restrict__ w_u,
    const float* __restrict__ w_d,
    _Float16* __restrict__ wgT, _Float16* __restrict__ wuT, _Float16* __restrict__ wdT,
    int* __restrict__ counts, int* __restrict__ tlist,
    int* __restrict__ t2e, int* __restrict__ t2pos, float* __restrict__ t2p) {
  __shared__ float tile[32][33];
  __shared__ int   s_cnt[E];
  __shared__ int   s_base[E];
  __shared__ int   s_e[2 * TOKB];
  __shared__ int   s_pos[2 * TOKB];
  __shared__ float s_p[2 * TOKB];
  int bid = blockIdx.x;

  if (bid < RTB) {
    // ---- router for tokens [bid*TOKB, +TOKB) ----
    int wv = threadIdx.x >> 6, lane = threadIdx.x & 63;
    if (threadIdx.x < E) s_cnt[threadIdx.x] = 0;
    __syncthreads();
    for (int j = 0; j < TOKB / 4; ++j) {
      int tl = wv * (TOKB / 4) + j;
      int t  = bid * TOKB + tl;
      const float* xr = x + (size_t)t * D;
      float acc[E] = {0.f,0.f,0.f,0.f,0.f,0.f,0.f,0.f};
      #pragma unroll
      for (int i = 0; i < D / 64; ++i) {
        int d = i * 64 + lane;
        float xv = xr[d];
        const float4* wr2 = (const float4*)(wgate + (size_t)d * E);
        float4 w0 = wr2[0], w1 = wr2[1];
        acc[0] += xv * w0.x; acc[1] += xv * w0.y; acc[2] += xv * w0.z; acc[3] += xv * w0.w;
        acc[4] += xv * w1.x; acc[5] += xv * w1.y; acc[6] += xv * w1.z; acc[7] += xv * w1.w;
      }
      #pragma unroll
      for (int e = 0; e < E; ++e) {
        #pragma unroll
        for (int off = 32; off; off >>= 1) acc[e] += __shfl_xor(acc[e], off, 64);
      }
      if (lane == 0) {
        int i0 = 0; float s0 = acc[0];
        #pragma unroll
        for (int e = 1; e < E; ++e) if (acc[e] > s0) { s0 = acc[e]; i0 = e; }
        int i1 = -1; float s1 = -1e30f;
        #pragma unroll
        for (int e = 0; e < E; ++e) if (e != i0 && acc[e] > s1) { s1 = acc[e]; i1 = e; }
        float p0 = 1.f / (1.f + expf(s1 - s0));
        float p1 = 1.f - p0;
        int q0 = atomicAdd(&s_cnt[i0], 1);
        int q1 = atomicAdd(&s_cnt[i1], 1);
        s_e[2 * tl]     = i0; s_pos[2 * tl]     = q0; s_p[2 * tl]     = p0;
        s_e[2 * tl + 1] = i1; s_pos[2 * tl + 1] = q1; s_p[2 * tl + 1] = p1;
      }
    }
    __syncthreads();
    if (threadIdx.x < E)
      s_base[threadIdx.x] = atomicAdd(&counts[threadIdx.x * CSTR], s_cnt[threadIdx.x]);
    __syncthreads();
    if (threadIdx.x < 2 * TOKB) {
      int sl = threadIdx.x;
      int e = s_e[sl];
      int pos = s_base[e] + s_pos[sl];
      int t = bid * TOKB + (sl >> 1);
      tlist[e * T + pos] = t;
      t2e[2 * t + (sl & 1)]   = e;
      t2pos[2 * t + (sl & 1)] = pos;
      t2p[2 * t + (sl & 1)]   = s_p[sl];
    }
    return;
  }

  // ---- transpose-convert [E][R][C] f32 -> [E][C][R] f16 ----
  int i = bid - RTB;
  int which = i / TP_PER_W;
  int j = i - which * TP_PER_W;
  const float* src; _Float16* dst; int Rr, Cc;
  if (which == 0)      { src = w_g; dst = wgT; Rr = D; Cc = M; }
  else if (which == 1) { src = w_u; dst = wuT; Rr = D; Cc = M; }
  else                 { src = w_d; dst = wdT; Rr = M; Cc = D; }
  int ctn = Cc / 32, rtn = Rr / 32;
  int e   = j / (ctn * rtn);
  int rem = j - e * (ctn * rtn);
  int rt = rem / ctn, ct = rem - rt * ctn;
  int tr  = threadIdx.x >> 3;
  int tc4 = (threadIdx.x & 7) * 4;
  const float* s = src + ((size_t)e * Rr + rt * 32 + tr) * Cc + ct * 32 + tc4;
  float4 v = *(const float4*)s;
  tile[tr][tc4 + 0] = v.x; tile[tr][tc4 + 1] = v.y;
  tile[tr][tc4 + 2] = v.z; tile[tr][tc4 + 3] = v.w;
  __syncthreads();
  union { _Float16 h[4]; ushort4 u; } o;
  #pragma unroll
  for (int q = 0; q < 4; ++q) o.h[q] = (_Float16)tile[tc4 + q][tr];
  *(ushort4*)(dst + ((size_t)e * Cc + ct * 32 + tr) * Rr + rt * 32 + tc4) = o.u;
}

// ---------------- gather tokens -> fp16, zero pad rows ----------------
__global__ __launch_bounds__(256) void k_gather(
    const float* __restrict__ x, const int* __restrict__ counts,
    const int* __restrict__ tlist, _Float16* __restrict__ Xg) {
  int r = blockIdx.x;
  int b = 0, e = -1, local = 0, cnt = 0;
  #pragma unroll
  for (int ee = 0; ee < E; ++ee) {
    int c = counts[ee * CSTR];
    int p = (c + TM - 1) / TM * TM;
    if (e < 0 && r < b + p) { e = ee; local = r - b; cnt = c; }
    b += p;
  }
  if (e < 0) return;
  int d = threadIdx.x * 4;
  union { _Float16 h[4]; ushort4 u; } o;
  if (local < cnt) {
    int t = tlist[e * T + local];
    float4 v = *(const float4*)(x + (size_t)t * D + d);
    o.h[0] = (_Float16)v.x; o.h[1] = (_Float16)v.y;
    o.h[2] = (_Float16)v.z; o.h[3] = (_Float16)v.w;
  } else {
    o.h[0] = (_Float16)0.f; o.h[1] = (_Float16)0.f;
    o.h[2] = (_Float16)0.f; o.h[3] = (_Float16)0.f;
  }
  *(ushort4*)(Xg + (size_t)r * D + d) = o.u;
}

// ---------------- fused gate+up grouped GEMM + SiLU (BK=64, XOR-swizzled LDS) --
// Swizzle (rule #21, both-sides): global_load_lds writes LINEARLY, so the
// permutation is applied on the per-lane GLOBAL source (chunk ^= row&7) and
// the ds_read side applies the same XOR.
// __launch_bounds__(256,2): accumulators need 128 AGPRs/wave; 3 waves/EU
// (round 2) forced the allocator to spill them to scratch -> 10x WRITE_SIZE.
__global__ __launch_bounds__(256, 2) void k_upgate(
    const _Float16* __restrict__ Xg, const _Float16* __restrict__ wgT,
    const _Float16* __restrict__ wuT, _Float16* __restrict__ Hid,
    const int* __restrict__ counts) {
  int lin = blockIdx.x;
  int e = lin & 7;
  int r = lin >> 3;
  int nt = r % NT_UP;
  int mt = r / NT_UP;
  int base_e, pc_e;
  expert_base_pc(counts, e, base_e, pc_e);
  if (mt * TM >= pc_e) return;
  int row0 = base_e + mt * TM;
  int n0 = nt * TN;
  __shared__ _Float16 As[TM * BK];   // 16 KB
  __shared__ _Float16 Bg[TN * BK];   // 16 KB
  __shared__ _Float16 Bu[TN * BK];   // 16 KB
  int tid = threadIdx.x;
  int w = tid >> 6, lane = tid & 63;
  int lrow = lane & 15, quad = lane >> 4;
  int wr = w >> 1, wc = w & 1;
  int sr = lane >> 3;                      // staging row within 8-row group
  int sc = (((lane & 7) ^ sr) & 7) * 8;    // pre-swizzled global k-chunk (halves)

  const _Float16* wg_e = wgT + (size_t)e * M * D;
  const _Float16* wu_e = wuT + (size_t)e * M * D;
  const _Float16* pA[4]; const _Float16* pG[4]; const _Float16* pU[4];
  char* lA[4]; char* lG[4]; char* lU[4];
  #pragma unroll
  for (int rr = 0; rr < 4; ++rr) {
    int grow = w * 32 + rr * 8 + sr;
    pA[rr] = Xg   + (size_t)(row0 + grow) * D + sc;
    pG[rr] = wg_e + (size_t)(n0   + grow) * D + sc;
    pU[rr] = wu_e + (size_t)(n0   + grow) * D + sc;
    lA[rr] = (char*)As + (w * 4 + rr) * 1024;
    lG[rr] = (char*)Bg + (w * 4 + rr) * 1024;
    lU[rr] = (char*)Bu + (w * 4 + rr) * 1024;
  }

  // swizzled read chunk indices (row&7 == lrow&7 since wr*64, i*16 are mult of 8)
  int swA = lrow & 7;
  int swB = lrow & 7;

  floatx4 accg[4][4] = {};   // [c][i]
  floatx4 accu[4][4] = {};

  for (int k0 = 0; k0 < D; k0 += BK) {
    #pragma unroll
    for (int rr = 0; rr < 4; ++rr) {
      gl_lds16(pA[rr], lA[rr]);
      gl_lds16(pG[rr], lG[rr]);
      gl_lds16(pU[rr], lU[rr]);
      pA[rr] += BK; pG[rr] += BK; pU[rr] += BK;
    }
    __syncthreads();
    #pragma unroll
    for (int c2 = 0; c2 < 2; ++c2) {
      half8 af[4];
      #pragma unroll
      for (int i = 0; i < 4; ++i)
        af[i] = *(const half8*)&As[(wr * 64 + i * 16 + lrow) * BK +
                                   (((c2 * 4 + quad) ^ swA) * 8)];
      #pragma unroll
      for (int c = 0; c < 4; ++c) {
        int bo = (wc * 64 + c * 16 + lrow) * BK + (((c2 * 4 + quad) ^ swB) * 8);
        half8 bgc = *(const half8*)&Bg[bo];
        half8 buc = *(const half8*)&Bu[bo];
        #pragma unroll
        for (int i = 0; i < 4; ++i) {
          accg[c][i] = __builtin_amdgcn_mfma_f32_16x16x32_f16(af[i], bgc, accg[c][i], 0, 0, 0);
          accu[c][i] = __builtin_amdgcn_mfma_f32_16x16x32_f16(af[i], buc, accu[c][i], 0, 0, 0);
        }
      }
    }
    __syncthreads();
  }
  #pragma unroll
  for (int c = 0; c < 4; ++c) {
    int col = n0 + wc * 64 + c * 16 + lrow;
    #pragma unroll
    for (int i = 0; i < 4; ++i) {
      int rowb = row0 + wr * 64 + i * 16 + quad * 4;
      #pragma unroll
      for (int reg = 0; reg < 4; ++reg) {
        float g = accg[c][i][reg], u = accu[c][i][reg];
        Hid[(size_t)(rowb + reg) * M + col] = (_Float16)(g / (1.f + expf(-g)) * u);
      }
    }
  }
}

// ---------------- down grouped GEMM -> per-slot rows Yp (BK=64, swizzled) ----
__global__ __launch_bounds__(256, 2) void k_down(
    const _Float16* __restrict__ Hid, const _Float16* __restrict__ wdT,
    _Float16* __restrict__ Yp, const int* __restrict__ counts) {
  int lin = blockIdx.x;
  int e = lin & 7;
  int r = lin >> 3;
  int nt = r % NT_DN;
  int mt = r / NT_DN;
  int base_e, pc_e;
  expert_base_pc(counts, e, base_e, pc_e);
  if (mt * TM >= pc_e) return;
  int row0 = base_e + mt * TM;
  int d0 = nt * TN;
  __shared__ _Float16 As[TM * BK];   // 16 KB
  __shared__ _Float16 Bs[TN * BK];   // 16 KB
  int tid = threadIdx.x;
  int w = tid >> 6, lane = tid & 63;
  int lrow = lane & 15, quad = lane >> 4;
  int wr = w >> 1, wc = w & 1;
  int sr = lane >> 3;
  int sc = (((lane & 7) ^ sr) & 7) * 8;

  const _Float16* wd_e = wdT + (size_t)e * D * M;
  const _Float16* pA[4]; const _Float16* pB[4];
  char* lA[4]; char* lB[4];
  #pragma unroll
  for (int rr = 0; rr < 4; ++rr) {
    int grow = w * 32 + rr * 8 + sr;
    pA[rr] = Hid  + (size_t)(row0 + grow) * M + sc;
    pB[rr] = wd_e + (size_t)(d0   + grow) * M + sc;
    lA[rr] = (char*)As + (w * 4 + rr) * 1024;
    lB[rr] = (char*)Bs + (w * 4 + rr) * 1024;
  }

  int sw = lrow & 7;

  floatx4 acc[4][4] = {};

  for (int k0 = 0; k0 < M; k0 += BK) {
    #pragma unroll
    for (int rr = 0; rr < 4; ++rr) {
      gl_lds16(pA[rr], lA[rr]);
      gl_lds16(pB[rr], lB[rr]);
      pA[rr] += BK; pB[rr] += BK;
    }
    __syncthreads();
    #pragma unroll
    for (int c2 = 0; c2 < 2; ++c2) {
      half8 af[4];
      #pragma unroll
      for (int i = 0; i < 4; ++i)
        af[i] = *(const half8*)&As[(wr * 64 + i * 16 + lrow) * BK +
                                   (((c2 * 4 + quad) ^ sw) * 8)];
      #pragma unroll
      for (int c = 0; c < 4; ++c) {
        half8 bc = *(const half8*)&Bs[(wc * 64 + c * 16 + lrow) * BK +
                                      (((c2 * 4 + quad) ^ sw) * 8)];
        #pragma unroll
        for (int i = 0; i < 4; ++i)
          acc[c][i] = __builtin_amdgcn_mfma_f32_16x16x32_f16(af[i], bc, acc[c][i], 0, 0, 0);
      }
    }
    __syncthreads();
  }
  #pragma unroll
  for (int c = 0; c < 4; ++c) {
    int col = d0 + wc * 64 + c * 16 + lrow;
    #pragma unroll
    for (int i = 0; i < 4; ++i) {
      int rowb = row0 + wr * 64 + i * 16 + quad * 4;
      #pragma unroll
      for (int reg = 0; reg < 4; ++reg)
        Yp[(size_t)(rowb + reg) * D + col] = (_Float16)acc[c][i][reg];
    }
  }
}

// ---------------- combine: y[t] = p0*Yp[r0] + p1*Yp[r1] ----------------
__global__ __launch_bounds__(256) void k_combine(
    const _Float16* __restrict__ Yp, const int* __restrict__ counts,
    const int* __restrict__ t2e, const int* __restrict__ t2pos,
    const float* __restrict__ t2p, float* __restrict__ out) {
  int t = blockIdx.x;
  int e0 = t2e[2 * t], e1 = t2e[2 * t + 1];
  int b = 0, b0 = 0, b1 = 0;
  #pragma unroll
  for (int ee = 0; ee < E; ++ee) {
    if (ee == e0) b0 = b;
    if (ee == e1) b1 = b;
    int c = counts[ee * CSTR];
    b += (c + TM - 1) / TM * TM;
  }
  int r0 = b0 + t2pos[2 * t];
  int r1 = b1 + t2pos[2 * t + 1];
  float p0 = t2p[2 * t], p1 = t2p[2 * t + 1];
  int d = threadIdx.x * 4;
  half4 h0 = *(const half4*)(Yp + (size_t)r0 * D + d);
  half4 h1 = *(const half4*)(Yp + (size_t)r1 * D + d);
  float4 o;
  o.x = p0 * (float)h0.x + p1 * (float)h1.x;
  o.y = p0 * (float)h0.y + p1 * (float)h1.y;
  o.z = p0 * (float)h0.z + p1 * (float)h1.z;
  o.w = p0 * (float)h0.w + p1 * (float)h1.w;
  *(float4*)(out + (size_t)t * D + d) = o;
}

// ---------------- launch ----------------
extern "C" void kernel_launch(void* const* d_in, const int* in_sizes, int n_in,
                              void* d_out, int out_size, void* d_ws, size_t ws_size,
                              hipStream_t stream) {
  const float* x     = (const float*)d_in[0];
  const float* wgate = (const float*)d_in[1];
  const float* w_g   = (const float*)d_in[2];
  const float* w_u   = (const float*)d_in[3];
  const float* w_d   = (const float*)d_in[4];
  float* out = (float*)d_out;
  char* ws = (char*)d_ws;

  if (ws_size < WS_NEED) {
    fprintf(stderr, "kernel_launch: ws_size=%zu < needed %zu\n", ws_size, WS_NEED);
    return;
  }

  int* counts = (int*)(ws + OFF_COUNTS);
  int* t2e    = (int*)(ws + OFF_T2E);
  int* t2pos  = (int*)(ws + OFF_T2POS);
  float* t2p  = (float*)(ws + OFF_T2P);
  int* tlist  = (int*)(ws + OFF_TLIST);
  _Float16* Xg  = (_Float16*)(ws + OFF_XG);   // later reused as Yp
  _Float16* Hid = (_Float16*)(ws + OFF_HID);
  _Float16* wgT = (_Float16*)(ws + OFF_WGT);
  _Float16* wuT = (_Float16*)(ws + OFF_WUT);
  _Float16* wdT = (_Float16*)(ws + OFF_WDT);

  hipMemsetAsync(counts, 0, (size_t)E * CSTR * 4, stream);

  k_prep<<<PREP_GRID, 256, 0, stream>>>(x, wgate, w_g, w_u, w_d,
                                        wgT, wuT, wdT,
                                        counts, tlist, t2e, t2pos, t2p);
  k_gather<<<RCAP, 256, 0, stream>>>(x, counts, tlist, Xg);
  k_upgate<<<E * MT_MAX * NT_UP, 256, 0, stream>>>(Xg, wgT, wuT, Hid, counts);
  _Float16* Yp = Xg;   // Xg dead; reuse as Yp
  k_down<<<E * MT_MAX * NT_DN, 256, 0, stream>>>(Hid, wdT, Yp, counts);
  k_combine<<<T, 256, 0, stream>>>(Yp, counts, t2e, t2pos, t2p, out);
}

// Round 5
// 330.275 us; speedup vs baseline: 1.2331x; 1.0056x over previous
//
#include <hip/hip_runtime.h>
#include <cstdio>

// ---------------- problem constants ----------------
constexpr int T  = 4096;       // B*S tokens
constexpr int D  = 1024;       // n_embed
constexpr int M  = 1408;       // n_moe_mlp
constexpr int E  = 8;          // experts

constexpr int TM = 128;        // token-rows per tile
constexpr int BK = 64;         // K-step
constexpr int TN_UP = 64;      // upgate output cols per tile (halved: acc fits (256,3))
constexpr int TN_DN = 128;     // down output cols per tile
constexpr int RCAP = T * 2 + E * TM;  // 9216 padded row capacity
constexpr int MT_MAX = T / TM; // 32 row-tiles max per expert
constexpr int NT_UP = M / TN_UP;  // 22
constexpr int NT_DN = D / TN_DN;  // 8

constexpr int CSTR = 64;       // per-expert counter stride in ints (256 B)
constexpr int TOKB = 16;       // tokens per router block (16 -> 256 router blocks)
constexpr int RTB  = T / TOKB; // 256 router blocks
constexpr int TP_PER_W = (M / 32) * (D / 32) * E;  // 11264 transpose blocks per weight
constexpr int PREP_GRID = RTB + 3 * TP_PER_W;      // 34048

typedef _Float16 half8 __attribute__((ext_vector_type(8)));
typedef _Float16 half4 __attribute__((ext_vector_type(4)));
typedef float    floatx4 __attribute__((ext_vector_type(4)));

// ---------------- ws layout (bytes) ----------------
constexpr size_t OFF_COUNTS = 0;                               // E*CSTR ints
constexpr size_t OFF_BASE   = (size_t)E * CSTR * 4;            // (legacy, unused)
constexpr size_t OFF_PC     = OFF_BASE + 64;
constexpr size_t OFF_TOTAL  = OFF_PC + 64;
constexpr size_t OFF_T2E    = OFF_TOTAL + 64;                  // 2T ints
constexpr size_t OFF_T2POS  = OFF_T2E   + (size_t)2 * T * 4;
constexpr size_t OFF_T2P    = OFF_T2POS + (size_t)2 * T * 4;
constexpr size_t OFF_TLIST  = OFF_T2P   + (size_t)2 * T * 4;   // E*T ints
constexpr size_t OFF_XG     = OFF_TLIST + (size_t)E * T * 4;   // RCAP x D fp16 (reused as Yp)
constexpr size_t OFF_HID    = OFF_XG  + (size_t)RCAP * D * 2;  // RCAP x M fp16
constexpr size_t OFF_WGT    = OFF_HID + (size_t)RCAP * M * 2;  // E x M x D fp16
constexpr size_t OFF_WUT    = OFF_WGT + (size_t)E * M * D * 2;
constexpr size_t OFF_WDT    = OFF_WUT + (size_t)E * M * D * 2; // E x D x M fp16
constexpr size_t WS_NEED    = OFF_WDT + (size_t)E * D * M * 2;

// async global->LDS, 16B per lane. LDS dest = wave-uniform base + lane*16.
__device__ __forceinline__ void gl_lds16(const void* g, void* l) {
  __builtin_amdgcn_global_load_lds(
      (const __attribute__((address_space(1))) unsigned int*)g,
      (__attribute__((address_space(3))) unsigned int*)l, 16, 0, 0);
}

// 8-expert padded prefix via uniform scalar loads.
__device__ __forceinline__ void expert_base_pc(const int* __restrict__ counts,
                                               int e, int& base_e, int& pc_e) {
  int b = 0; base_e = 0; pc_e = 0;
  #pragma unroll
  for (int ee = 0; ee < E; ++ee) {
    int c = counts[ee * CSTR];
    int p = (c + TM - 1) / TM * TM;
    if (ee == e) { base_e = b; pc_e = p; }
    b += p;
  }
}

// ---------------- fused prep: router blocks + weight-transpose blocks ----------
__global__ __launch_bounds__(256) void k_prep(
    const float* __restrict__ x, const float* __restrict__ wgate,
    const float* __restrict__ w_g, const float* __restrict__ w_u,
    const float* __restrict__ w_d,
    _Float16* __restrict__ wgT, _Float16* __restrict__ wuT, _Float16* __restrict__ wdT,
    int* __restrict__ counts, int* __restrict__ tlist,
    int* __restrict__ t2e, int* __restrict__ t2pos, float* __restrict__ t2p) {
  __shared__ float tile[32][33];
  __shared__ int   s_cnt[E];
  __shared__ int   s_base[E];
  __shared__ int   s_e[2 * TOKB];
  __shared__ int   s_pos[2 * TOKB];
  __shared__ float s_p[2 * TOKB];
  int bid = blockIdx.x;

  if (bid < RTB) {
    // ---- router for tokens [bid*TOKB, +TOKB) ----
    int wv = threadIdx.x >> 6, lane = threadIdx.x & 63;
    if (threadIdx.x < E) s_cnt[threadIdx.x] = 0;
    __syncthreads();
    for (int j = 0; j < TOKB / 4; ++j) {
      int tl = wv * (TOKB / 4) + j;
      int t  = bid * TOKB + tl;
      const float* xr = x + (size_t)t * D;
      float acc[E] = {0.f,0.f,0.f,0.f,0.f,0.f,0.f,0.f};
      #pragma unroll
      for (int i = 0; i < D / 64; ++i) {
        int d = i * 64 + lane;
        float xv = xr[d];
        const float4* wr2 = (const float4*)(wgate + (size_t)d * E);
        float4 w0 = wr2[0], w1 = wr2[1];
        acc[0] += xv * w0.x; acc[1] += xv * w0.y; acc[2] += xv * w0.z; acc[3] += xv * w0.w;
        acc[4] += xv * w1.x; acc[5] += xv * w1.y; acc[6] += xv * w1.z; acc[7] += xv * w1.w;
      }
      #pragma unroll
      for (int e = 0; e < E; ++e) {
        #pragma unroll
        for (int off = 32; off; off >>= 1) acc[e] += __shfl_xor(acc[e], off, 64);
      }
      if (lane == 0) {
        int i0 = 0; float s0 = acc[0];
        #pragma unroll
        for (int e = 1; e < E; ++e) if (acc[e] > s0) { s0 = acc[e]; i0 = e; }
        int i1 = -1; float s1 = -1e30f;
        #pragma unroll
        for (int e = 0; e < E; ++e) if (e != i0 && acc[e] > s1) { s1 = acc[e]; i1 = e; }
        float p0 = 1.f / (1.f + expf(s1 - s0));
        float p1 = 1.f - p0;
        int q0 = atomicAdd(&s_cnt[i0], 1);
        int q1 = atomicAdd(&s_cnt[i1], 1);
        s_e[2 * tl]     = i0; s_pos[2 * tl]     = q0; s_p[2 * tl]     = p0;
        s_e[2 * tl + 1] = i1; s_pos[2 * tl + 1] = q1; s_p[2 * tl + 1] = p1;
      }
    }
    __syncthreads();
    if (threadIdx.x < E)
      s_base[threadIdx.x] = atomicAdd(&counts[threadIdx.x * CSTR], s_cnt[threadIdx.x]);
    __syncthreads();
    if (threadIdx.x < 2 * TOKB) {
      int sl = threadIdx.x;
      int e = s_e[sl];
      int pos = s_base[e] + s_pos[sl];
      int t = bid * TOKB + (sl >> 1);
      tlist[e * T + pos] = t;
      t2e[2 * t + (sl & 1)]   = e;
      t2pos[2 * t + (sl & 1)] = pos;
      t2p[2 * t + (sl & 1)]   = s_p[sl];
    }
    return;
  }

  // ---- transpose-convert [E][R][C] f32 -> [E][C][R] f16 ----
  int i = bid - RTB;
  int which = i / TP_PER_W;
  int j = i - which * TP_PER_W;
  const float* src; _Float16* dst; int Rr, Cc;
  if (which == 0)      { src = w_g; dst = wgT; Rr = D; Cc = M; }
  else if (which == 1) { src = w_u; dst = wuT; Rr = D; Cc = M; }
  else                 { src = w_d; dst = wdT; Rr = M; Cc = D; }
  int ctn = Cc / 32, rtn = Rr / 32;
  int e   = j / (ctn * rtn);
  int rem = j - e * (ctn * rtn);
  int rt = rem / ctn, ct = rem - rt * ctn;
  int tr  = threadIdx.x >> 3;
  int tc4 = (threadIdx.x & 7) * 4;
  const float* s = src + ((size_t)e * Rr + rt * 32 + tr) * Cc + ct * 32 + tc4;
  float4 v = *(const float4*)s;
  tile[tr][tc4 + 0] = v.x; tile[tr][tc4 + 1] = v.y;
  tile[tr][tc4 + 2] = v.z; tile[tr][tc4 + 3] = v.w;
  __syncthreads();
  union { _Float16 h[4]; ushort4 u; } o;
  #pragma unroll
  for (int q = 0; q < 4; ++q) o.h[q] = (_Float16)tile[tc4 + q][tr];
  *(ushort4*)(dst + ((size_t)e * Cc + ct * 32 + tr) * Rr + rt * 32 + tc4) = o.u;
}

// ---------------- gather tokens -> fp16, zero pad rows ----------------
__global__ __launch_bounds__(256) void k_gather(
    const float* __restrict__ x, const int* __restrict__ counts,
    const int* __restrict__ tlist, _Float16* __restrict__ Xg) {
  int r = blockIdx.x;
  int b = 0, e = -1, local = 0, cnt = 0;
  #pragma unroll
  for (int ee = 0; ee < E; ++ee) {
    int c = counts[ee * CSTR];
    int p = (c + TM - 1) / TM * TM;
    if (e < 0 && r < b + p) { e = ee; local = r - b; cnt = c; }
    b += p;
  }
  if (e < 0) return;
  int d = threadIdx.x * 4;
  union { _Float16 h[4]; ushort4 u; } o;
  if (local < cnt) {
    int t = tlist[e * T + local];
    float4 v = *(const float4*)(x + (size_t)t * D + d);
    o.h[0] = (_Float16)v.x; o.h[1] = (_Float16)v.y;
    o.h[2] = (_Float16)v.z; o.h[3] = (_Float16)v.w;
  } else {
    o.h[0] = (_Float16)0.f; o.h[1] = (_Float16)0.f;
    o.h[2] = (_Float16)0.f; o.h[3] = (_Float16)0.f;
  }
  *(ushort4*)(Xg + (size_t)r * D + d) = o.u;
}

// ---------------- fused gate+up grouped GEMM + SiLU ----------------
// TM=128 x TN_UP=64 tile, 4 waves each owning 64x32 per GEMM: acc = 64 regs
// -> fits (256,3) without spill (round-2 spill was 128 acc at the 170 budget).
// 3 blocks/CU: capacity 768 blocks; 1408 working half-size blocks -> tail
// waste ~halved vs 704 full-size blocks on 512 slots.
// LDS XOR-swizzle on both sides (global source pre-swizzle + ds_read XOR).
__global__ __launch_bounds__(256, 3) void k_upgate(
    const _Float16* __restrict__ Xg, const _Float16* __restrict__ wgT,
    const _Float16* __restrict__ wuT, _Float16* __restrict__ Hid,
    const int* __restrict__ counts) {
  int lin = blockIdx.x;
  int e = lin & 7;
  int r = lin >> 3;
  int nt = r % NT_UP;
  int mt = r / NT_UP;
  int base_e, pc_e;
  expert_base_pc(counts, e, base_e, pc_e);
  if (mt * TM >= pc_e) return;
  int row0 = base_e + mt * TM;
  int n0 = nt * TN_UP;
  __shared__ _Float16 As[TM * BK];      // 16 KB
  __shared__ _Float16 Bg[TN_UP * BK];   // 8 KB
  __shared__ _Float16 Bu[TN_UP * BK];   // 8 KB
  int tid = threadIdx.x;
  int w = tid >> 6, lane = tid & 63;
  int lrow = lane & 15, quad = lane >> 4;
  int wr = w >> 1, wc = w & 1;           // wave owns rows wr*64.., cols wc*32..
  int sr = lane >> 3;                    // staging row within 8-row group
  int sc = (((lane & 7) ^ sr) & 7) * 8;  // pre-swizzled global k-chunk (halves)

  const _Float16* wg_e = wgT + (size_t)e * M * D;
  const _Float16* wu_e = wuT + (size_t)e * M * D;
  const _Float16* pA[4]; char* lA[4];
  const _Float16* pG[2]; const _Float16* pU[2]; char* lG[2]; char* lU[2];
  #pragma unroll
  for (int rr = 0; rr < 4; ++rr) {
    int grow = w * 32 + rr * 8 + sr;       // A rows 0..127
    pA[rr] = Xg + (size_t)(row0 + grow) * D + sc;
    lA[rr] = (char*)As + (w * 4 + rr) * 1024;
  }
  #pragma unroll
  for (int j = 0; j < 2; ++j) {
    int brow = w * 16 + j * 8 + sr;        // B rows 0..63
    pG[j] = wg_e + (size_t)(n0 + brow) * D + sc;
    pU[j] = wu_e + (size_t)(n0 + brow) * D + sc;
    lG[j] = (char*)Bg + (w * 2 + j) * 1024;
    lU[j] = (char*)Bu + (w * 2 + j) * 1024;
  }

  int sw = lrow & 7;  // read-side swizzle (row&7 == lrow&7: bases are mult of 8)

  floatx4 accg[4][2] = {};   // [i][c]
  floatx4 accu[4][2] = {};

  for (int k0 = 0; k0 < D; k0 += BK) {
    #pragma unroll
    for (int rr = 0; rr < 4; ++rr) { gl_lds16(pA[rr], lA[rr]); pA[rr] += BK; }
    #pragma unroll
    for (int j = 0; j < 2; ++j) {
      gl_lds16(pG[j], lG[j]); pG[j] += BK;
      gl_lds16(pU[j], lU[j]); pU[j] += BK;
    }
    __syncthreads();
    #pragma unroll
    for (int c2 = 0; c2 < 2; ++c2) {
      int kc = ((c2 * 4 + quad) ^ sw) * 8;
      half8 af[4];
      #pragma unroll
      for (int i = 0; i < 4; ++i)
        af[i] = *(const half8*)&As[(wr * 64 + i * 16 + lrow) * BK + kc];
      #pragma unroll
      for (int c = 0; c < 2; ++c) {
        int bo = (wc * 32 + c * 16 + lrow) * BK + kc;
        half8 bgc = *(const half8*)&Bg[bo];
        half8 buc = *(const half8*)&Bu[bo];
        #pragma unroll
        for (int i = 0; i < 4; ++i) {
          accg[i][c] = __builtin_amdgcn_mfma_f32_16x16x32_f16(af[i], bgc, accg[i][c], 0, 0, 0);
          accu[i][c] = __builtin_amdgcn_mfma_f32_16x16x32_f16(af[i], buc, accu[i][c], 0, 0, 0);
        }
      }
    }
    __syncthreads();
  }
  #pragma unroll
  for (int c = 0; c < 2; ++c) {
    int col = n0 + wc * 32 + c * 16 + lrow;
    #pragma unroll
    for (int i = 0; i < 4; ++i) {
      int rowb = row0 + wr * 64 + i * 16 + quad * 4;
      #pragma unroll
      for (int reg = 0; reg < 4; ++reg) {
        float g = accg[i][c][reg], u = accu[i][c][reg];
        Hid[(size_t)(rowb + reg) * M + col] = (_Float16)(g / (1.f + expf(-g)) * u);
      }
    }
  }
}

// ---------------- down grouped GEMM -> per-slot rows Yp (BK=64, swizzled) ----
// acc = 64 regs (single GEMM) -> (256,3) should not spill; 512 working blocks
// all resident in one scheduling round with occupancy headroom.
__global__ __launch_bounds__(256, 3) void k_down(
    const _Float16* __restrict__ Hid, const _Float16* __restrict__ wdT,
    _Float16* __restrict__ Yp, const int* __restrict__ counts) {
  int lin = blockIdx.x;
  int e = lin & 7;
  int r = lin >> 3;
  int nt = r % NT_DN;
  int mt = r / NT_DN;
  int base_e, pc_e;
  expert_base_pc(counts, e, base_e, pc_e);
  if (mt * TM >= pc_e) return;
  int row0 = base_e + mt * TM;
  int d0 = nt * TN_DN;
  __shared__ _Float16 As[TM * BK];      // 16 KB
  __shared__ _Float16 Bs[TN_DN * BK];   // 16 KB
  int tid = threadIdx.x;
  int w = tid >> 6, lane = tid & 63;
  int lrow = lane & 15, quad = lane >> 4;
  int wr = w >> 1, wc = w & 1;
  int sr = lane >> 3;
  int sc = (((lane & 7) ^ sr) & 7) * 8;

  const _Float16* wd_e = wdT + (size_t)e * D * M;
  const _Float16* pA[4]; const _Float16* pB[4];
  char* lA[4]; char* lB[4];
  #pragma unroll
  for (int rr = 0; rr < 4; ++rr) {
    int grow = w * 32 + rr * 8 + sr;
    pA[rr] = Hid  + (size_t)(row0 + grow) * M + sc;
    pB[rr] = wd_e + (size_t)(d0   + grow) * M + sc;
    lA[rr] = (char*)As + (w * 4 + rr) * 1024;
    lB[rr] = (char*)Bs + (w * 4 + rr) * 1024;
  }

  int sw = lrow & 7;

  floatx4 acc[4][4] = {};

  for (int k0 = 0; k0 < M; k0 += BK) {
    #pragma unroll
    for (int rr = 0; rr < 4; ++rr) {
      gl_lds16(pA[rr], lA[rr]);
      gl_lds16(pB[rr], lB[rr]);
      pA[rr] += BK; pB[rr] += BK;
    }
    __syncthreads();
    #pragma unroll
    for (int c2 = 0; c2 < 2; ++c2) {
      int kc = ((c2 * 4 + quad) ^ sw) * 8;
      half8 af[4];
      #pragma unroll
      for (int i = 0; i < 4; ++i)
        af[i] = *(const half8*)&As[(wr * 64 + i * 16 + lrow) * BK + kc];
      #pragma unroll
      for (int c = 0; c < 4; ++c) {
        half8 bc = *(const half8*)&Bs[(wc * 64 + c * 16 + lrow) * BK + kc];
        #pragma unroll
        for (int i = 0; i < 4; ++i)
          acc[c][i] = __builtin_amdgcn_mfma_f32_16x16x32_f16(af[i], bc, acc[c][i], 0, 0, 0);
      }
    }
    __syncthreads();
  }
  #pragma unroll
  for (int c = 0; c < 4; ++c) {
    int col = d0 + wc * 64 + c * 16 + lrow;
    #pragma unroll
    for (int i = 0; i < 4; ++i) {
      int rowb = row0 + wr * 64 + i * 16 + quad * 4;
      #pragma unroll
      for (int reg = 0; reg < 4; ++reg)
        Yp[(size_t)(rowb + reg) * D + col] = (_Float16)acc[c][i][reg];
    }
  }
}

// ---------------- combine: y[t] = p0*Yp[r0] + p1*Yp[r1] ----------------
__global__ __launch_bounds__(256) void k_combine(
    const _Float16* __restrict__ Yp, const int* __restrict__ counts,
    const int* __restrict__ t2e, const int* __restrict__ t2pos,
    const float* __restrict__ t2p, float* __restrict__ out) {
  int t = blockIdx.x;
  int e0 = t2e[2 * t], e1 = t2e[2 * t + 1];
  int b = 0, b0 = 0, b1 = 0;
  #pragma unroll
  for (int ee = 0; ee < E; ++ee) {
    if (ee == e0) b0 = b;
    if (ee == e1) b1 = b;
    int c = counts[ee * CSTR];
    b += (c + TM - 1) / TM * TM;
  }
  int r0 = b0 + t2pos[2 * t];
  int r1 = b1 + t2pos[2 * t + 1];
  float p0 = t2p[2 * t], p1 = t2p[2 * t + 1];
  int d = threadIdx.x * 4;
  half4 h0 = *(const half4*)(Yp + (size_t)r0 * D + d);
  half4 h1 = *(const half4*)(Yp + (size_t)r1 * D + d);
  float4 o;
  o.x = p0 * (float)h0.x + p1 * (float)h1.x;
  o.y = p0 * (float)h0.y + p1 * (float)h1.y;
  o.z = p0 * (float)h0.z + p1 * (float)h1.z;
  o.w = p0 * (float)h0.w + p1 * (float)h1.w;
  *(float4*)(out + (size_t)t * D + d) = o;
}

// ---------------- launch ----------------
extern "C" void kernel_launch(void* const* d_in, const int* in_sizes, int n_in,
                              void* d_out, int out_size, void* d_ws, size_t ws_size,
                              hipStream_t stream) {
  const float* x     = (const float*)d_in[0];
  const float* wgate = (const float*)d_in[1];
  const float* w_g   = (const float*)d_in[2];
  const float* w_u   = (const float*)d_in[3];
  const float* w_d   = (const float*)d_in[4];
  float* out = (float*)d_out;
  char* ws = (char*)d_ws;

  if (ws_size < WS_NEED) {
    fprintf(stderr, "kernel_launch: ws_size=%zu < needed %zu\n", ws_size, WS_NEED);
    return;
  }

  int* counts = (int*)(ws + OFF_COUNTS);
  int* t2e    = (int*)(ws + OFF_T2E);
  int* t2pos  = (int*)(ws + OFF_T2POS);
  float* t2p  = (float*)(ws + OFF_T2P);
  int* tlist  = (int*)(ws + OFF_TLIST);
  _Float16* Xg  = (_Float16*)(ws + OFF_XG);   // later reused as Yp
  _Float16* Hid = (_Float16*)(ws + OFF_HID);
  _Float16* wgT = (_Float16*)(ws + OFF_WGT);
  _Float16* wuT = (_Float16*)(ws + OFF_WUT);
  _Float16* wdT = (_Float16*)(ws + OFF_WDT);

  hipMemsetAsync(counts, 0, (size_t)E * CSTR * 4, stream);

  k_prep<<<PREP_GRID, 256, 0, stream>>>(x, wgate, w_g, w_u, w_d,
                                        wgT, wuT, wdT,
                                        counts, tlist, t2e, t2pos, t2p);
  k_gather<<<RCAP, 256, 0, stream>>>(x, counts, tlist, Xg);
  k_upgate<<<E * MT_MAX * NT_UP, 256, 0, stream>>>(Xg, wgT, wuT, Hid, counts);
  _Float16* Yp = Xg;   // Xg dead; reuse as Yp
  k_down<<<E * MT_MAX * NT_DN, 256, 0, stream>>>(Hid, wdT, Yp, counts);
  k_combine<<<T, 256, 0, stream>>>(Yp, counts, t2e, t2pos, t2p, out);
}

// Round 6
// 308.919 us; speedup vs baseline: 1.3183x; 1.0691x over previous
//
#include <hip/hip_runtime.h>
#include <cstdio>

// ---------------- problem constants ----------------
constexpr int T  = 4096;       // B*S tokens
constexpr int D  = 1024;       // n_embed
constexpr int M  = 1408;       // n_moe_mlp
constexpr int E  = 8;          // experts

constexpr int TM = 128;        // token-rows per tile
constexpr int TN = 128;        // output cols per tile
constexpr int BK = 32;         // K-step (32: dbuf LDS fits 2 blocks/CU)
constexpr int RCAP = T * 2 + E * TM;  // 9216 padded row capacity
constexpr int MT_MAX = T / TM; // 32 row-tiles max per expert
constexpr int NT_UP = M / TN;  // 11
constexpr int NT_DN = D / TN;  // 8

constexpr int CSTR = 64;       // per-expert counter stride in ints (256 B)
constexpr int TOKB = 16;       // tokens per router block
constexpr int RTB  = T / TOKB; // 256 router blocks
constexpr int XCV  = (T * D) / 2048;               // 2048 x->fp16 convert blocks
constexpr int TP_PER_W = (M / 32) * (D / 32) * E;  // 11264 transpose blocks/weight
constexpr int PREP_GRID = RTB + XCV + 3 * TP_PER_W;

typedef _Float16 half8 __attribute__((ext_vector_type(8)));
typedef _Float16 half4 __attribute__((ext_vector_type(4)));
typedef float    floatx4 __attribute__((ext_vector_type(4)));

// ---------------- ws layout (bytes) ----------------
constexpr size_t OFF_COUNTS = 0;                               // E*CSTR ints
constexpr size_t OFF_BASE   = (size_t)E * CSTR * 4;
constexpr size_t OFF_PC     = OFF_BASE + 64;
constexpr size_t OFF_TOTAL  = OFF_PC + 64;
constexpr size_t OFF_T2E    = OFF_TOTAL + 64;                  // 2T ints
constexpr size_t OFF_T2POS  = OFF_T2E   + (size_t)2 * T * 4;
constexpr size_t OFF_T2P    = OFF_T2POS + (size_t)2 * T * 4;
constexpr size_t OFF_TLIST  = OFF_T2P   + (size_t)2 * T * 4;   // E*T ints
constexpr size_t OFF_XG     = OFF_TLIST + (size_t)E * T * 4;   // Xh (T x D f16) then Yp (RCAP x D f16)
constexpr size_t OFF_HID    = OFF_XG  + (size_t)RCAP * D * 2;  // RCAP x M fp16
constexpr size_t OFF_WGT    = OFF_HID + (size_t)RCAP * M * 2;  // E x M x D fp16
constexpr size_t OFF_WUT    = OFF_WGT + (size_t)E * M * D * 2;
constexpr size_t OFF_WDT    = OFF_WUT + (size_t)E * M * D * 2; // E x D x M fp16
constexpr size_t WS_NEED    = OFF_WDT + (size_t)E * D * M * 2;

// async global->LDS, 16B per lane. LDS dest = wave-uniform base + lane*16;
// GLOBAL source is per-lane (enables gather + source-side swizzle).
__device__ __forceinline__ void gl_lds16(const void* g, void* l) {
  __builtin_amdgcn_global_load_lds(
      (const __attribute__((address_space(1))) unsigned int*)g,
      (__attribute__((address_space(3))) unsigned int*)l, 16, 0, 0);
}

// 8-expert padded prefix via uniform scalar loads.
__device__ __forceinline__ void expert_base_pc(const int* __restrict__ counts,
                                               int e, int& base_e, int& pc_e,
                                               int& cnt_e) {
  int b = 0; base_e = 0; pc_e = 0; cnt_e = 0;
  #pragma unroll
  for (int ee = 0; ee < E; ++ee) {
    int c = counts[ee * CSTR];
    int p = (c + TM - 1) / TM * TM;
    if (ee == e) { base_e = b; pc_e = p; cnt_e = c; }
    b += p;
  }
}

// ---------------- fused prep: router + x->f16 convert + weight transposes ------
__global__ __launch_bounds__(256) void k_prep(
    const float* __restrict__ x, const float* __restrict__ wgate,
    const float* __restrict__ w_g, const float* __restrict__ w_u,
    const float* __restrict__ w_d,
    _Float16* __restrict__ Xh,
    _Float16* __restrict__ wgT, _Float16* __restrict__ wuT, _Float16* __restrict__ wdT,
    int* __restrict__ counts, int* __restrict__ tlist,
    int* __restrict__ t2e, int* __restrict__ t2pos, float* __restrict__ t2p) {
  __shared__ float tile[32][33];
  __shared__ int   s_cnt[E];
  __shared__ int   s_base[E];
  __shared__ int   s_e[2 * TOKB];
  __shared__ int   s_pos[2 * TOKB];
  __shared__ float s_p[2 * TOKB];
  int bid = blockIdx.x;

  if (bid < RTB) {
    // ---- router for tokens [bid*TOKB, +TOKB) ----
    int wv = threadIdx.x >> 6, lane = threadIdx.x & 63;
    if (threadIdx.x < E) s_cnt[threadIdx.x] = 0;
    __syncthreads();
    for (int j = 0; j < TOKB / 4; ++j) {
      int tl = wv * (TOKB / 4) + j;
      int t  = bid * TOKB + tl;
      const float* xr = x + (size_t)t * D;
      float acc[E] = {0.f,0.f,0.f,0.f,0.f,0.f,0.f,0.f};
      #pragma unroll
      for (int i = 0; i < D / 64; ++i) {
        int d = i * 64 + lane;
        float xv = xr[d];
        const float4* wr2 = (const float4*)(wgate + (size_t)d * E);
        float4 w0 = wr2[0], w1 = wr2[1];
        acc[0] += xv * w0.x; acc[1] += xv * w0.y; acc[2] += xv * w0.z; acc[3] += xv * w0.w;
        acc[4] += xv * w1.x; acc[5] += xv * w1.y; acc[6] += xv * w1.z; acc[7] += xv * w1.w;
      }
      #pragma unroll
      for (int e = 0; e < E; ++e) {
        #pragma unroll
        for (int off = 32; off; off >>= 1) acc[e] += __shfl_xor(acc[e], off, 64);
      }
      if (lane == 0) {
        int i0 = 0; float s0 = acc[0];
        #pragma unroll
        for (int e = 1; e < E; ++e) if (acc[e] > s0) { s0 = acc[e]; i0 = e; }
        int i1 = -1; float s1 = -1e30f;
        #pragma unroll
        for (int e = 0; e < E; ++e) if (e != i0 && acc[e] > s1) { s1 = acc[e]; i1 = e; }
        float p0 = 1.f / (1.f + expf(s1 - s0));
        float p1 = 1.f - p0;
        int q0 = atomicAdd(&s_cnt[i0], 1);
        int q1 = atomicAdd(&s_cnt[i1], 1);
        s_e[2 * tl]     = i0; s_pos[2 * tl]     = q0; s_p[2 * tl]     = p0;
        s_e[2 * tl + 1] = i1; s_pos[2 * tl + 1] = q1; s_p[2 * tl + 1] = p1;
      }
    }
    __syncthreads();
    if (threadIdx.x < E)
      s_base[threadIdx.x] = atomicAdd(&counts[threadIdx.x * CSTR], s_cnt[threadIdx.x]);
    __syncthreads();
    if (threadIdx.x < 2 * TOKB) {
      int sl = threadIdx.x;
      int e = s_e[sl];
      int pos = s_base[e] + s_pos[sl];
      int t = bid * TOKB + (sl >> 1);
      tlist[e * T + pos] = t;
      t2e[2 * t + (sl & 1)]   = e;
      t2pos[2 * t + (sl & 1)] = pos;
      t2p[2 * t + (sl & 1)]   = s_p[sl];
    }
    return;
  }

  if (bid < RTB + XCV) {
    // ---- x (f32) -> Xh (f16), dense token-major ----
    size_t base = (size_t)(bid - RTB) * 2048 + threadIdx.x * 8;
    float4 v0 = *(const float4*)(x + base);
    float4 v1 = *(const float4*)(x + base + 4);
    half8 h;
    h[0] = (_Float16)v0.x; h[1] = (_Float16)v0.y;
    h[2] = (_Float16)v0.z; h[3] = (_Float16)v0.w;
    h[4] = (_Float16)v1.x; h[5] = (_Float16)v1.y;
    h[6] = (_Float16)v1.z; h[7] = (_Float16)v1.w;
    *(half8*)(Xh + base) = h;
    return;
  }

  // ---- transpose-convert [E][R][C] f32 -> [E][C][R] f16 ----
  int i = bid - RTB - XCV;
  int which = i / TP_PER_W;
  int j = i - which * TP_PER_W;
  const float* src; _Float16* dst; int Rr, Cc;
  if (which == 0)      { src = w_g; dst = wgT; Rr = D; Cc = M; }
  else if (which == 1) { src = w_u; dst = wuT; Rr = D; Cc = M; }
  else                 { src = w_d; dst = wdT; Rr = M; Cc = D; }
  int ctn = Cc / 32, rtn = Rr / 32;
  int e   = j / (ctn * rtn);
  int rem = j - e * (ctn * rtn);
  int rt = rem / ctn, ct = rem - rt * ctn;
  int tr  = threadIdx.x >> 3;
  int tc4 = (threadIdx.x & 7) * 4;
  const float* s = src + ((size_t)e * Rr + rt * 32 + tr) * Cc + ct * 32 + tc4;
  float4 v = *(const float4*)s;
  tile[tr][tc4 + 0] = v.x; tile[tr][tc4 + 1] = v.y;
  tile[tr][tc4 + 2] = v.z; tile[tr][tc4 + 3] = v.w;
  __syncthreads();
  union { _Float16 h[4]; ushort4 u; } o;
  #pragma unroll
  for (int q = 0; q < 4; ++q) o.h[q] = (_Float16)tile[tc4 + q][tr];
  *(ushort4*)(dst + ((size_t)e * Cc + ct * 32 + tr) * Rr + rt * 32 + tc4) = o.u;
}

// ---------------- fused gate+up grouped GEMM + SiLU ----------------
// Double-buffered LDS, ONE barrier per K-step: STAGE(next buf) is issued
// BEFORE compute(cur), so the vmcnt(0) drain inside __syncthreads() lands
// after a full compute phase -> global-load latency hidden (T3 min-2-phase).
// A rows gathered directly from dense Xh via per-lane tlist source addresses
// (global_load_lds source is per-lane) -- k_gather kernel eliminated.
// Swizzle (both-sides, rule #21): global source chunk ^= (row>>1)&3, ds_read
// applies the same XOR -> 2-way bank aliasing (free, m136).
__global__ __launch_bounds__(256, 2) void k_upgate(
    const _Float16* __restrict__ Xh, const _Float16* __restrict__ wgT,
    const _Float16* __restrict__ wuT, _Float16* __restrict__ Hid,
    const int* __restrict__ counts, const int* __restrict__ tlist) {
  int lin = blockIdx.x;
  int e = lin & 7;
  int r = lin >> 3;
  int nt = r % NT_UP;
  int mt = r / NT_UP;
  int base_e, pc_e, cnt_e;
  expert_base_pc(counts, e, base_e, pc_e, cnt_e);
  if (mt * TM >= pc_e) return;
  int row0 = base_e + mt * TM;
  int n0 = nt * TN;
  __shared__ _Float16 As[2][TM * BK];   // 2 x 8 KB
  __shared__ _Float16 Bg[2][TN * BK];   // 2 x 8 KB
  __shared__ _Float16 Bu[2][TN * BK];   // 2 x 8 KB
  int tid = threadIdx.x;
  int w = tid >> 6, lane = tid & 63;
  int lrow = lane & 15, quad = lane >> 4;
  int wr = w >> 1, wc = w & 1;
  int sr = lane >> 2;                         // staging row within 16-row group
  int c4 = lane & 3;                          // staging chunk
  int swc = ((c4 ^ ((sr >> 1) & 3))) * 8;     // pre-swizzled source chunk (halves)

  const _Float16* wg_e = wgT + (size_t)e * M * D;
  const _Float16* wu_e = wuT + (size_t)e * M * D;
  const _Float16* pA[2]; const _Float16* pG[2]; const _Float16* pU[2];
  int loff[2];
  #pragma unroll
  for (int is = 0; is < 2; ++is) {
    int grow = w * 32 + is * 16 + sr;         // tile row 0..127
    int local = mt * TM + grow;
    int trow = (local < cnt_e) ? tlist[e * T + local] : 0;  // pad-safe gather
    pA[is] = Xh   + (size_t)trow * D + swc;
    pG[is] = wg_e + (size_t)(n0 + grow) * D + swc;
    pU[is] = wu_e + (size_t)(n0 + grow) * D + swc;
    loff[is] = (w * 2 + is) * 1024;
  }

  int swr = (lrow >> 1) & 3;                  // read-side swizzle

  floatx4 accg[4][4] = {};   // [c][i]
  floatx4 accu[4][4] = {};

  auto stage = [&](int b) {
    char* a0 = (char*)&As[b][0];
    char* g0 = (char*)&Bg[b][0];
    char* u0 = (char*)&Bu[b][0];
    #pragma unroll
    for (int is = 0; is < 2; ++is) {
      gl_lds16(pA[is], a0 + loff[is]); pA[is] += BK;
      gl_lds16(pG[is], g0 + loff[is]); pG[is] += BK;
      gl_lds16(pU[is], u0 + loff[is]); pU[is] += BK;
    }
  };
  auto compute = [&](int b) {
    int kc = (quad ^ swr) * 8;
    half8 af[4];
    #pragma unroll
    for (int i = 0; i < 4; ++i)
      af[i] = *(const half8*)&As[b][(wr * 64 + i * 16 + lrow) * BK + kc];
    #pragma unroll
    for (int c = 0; c < 4; ++c) {
      int bo = (wc * 64 + c * 16 + lrow) * BK + kc;
      half8 bgc = *(const half8*)&Bg[b][bo];
      half8 buc = *(const half8*)&Bu[b][bo];
      #pragma unroll
      for (int i = 0; i < 4; ++i) {
        accg[c][i] = __builtin_amdgcn_mfma_f32_16x16x32_f16(af[i], bgc, accg[c][i], 0, 0, 0);
        accu[c][i] = __builtin_amdgcn_mfma_f32_16x16x32_f16(af[i], buc, accu[c][i], 0, 0, 0);
      }
    }
  };

  stage(0);
  __syncthreads();
  int cur = 0;
  for (int kt = 1; kt < D / BK; ++kt) {
    stage(cur ^ 1);
    compute(cur);
    __syncthreads();
    cur ^= 1;
  }
  compute(cur);

  #pragma unroll
  for (int c = 0; c < 4; ++c) {
    int col = n0 + wc * 64 + c * 16 + lrow;
    #pragma unroll
    for (int i = 0; i < 4; ++i) {
      int rowb = row0 + wr * 64 + i * 16 + quad * 4;
      #pragma unroll
      for (int reg = 0; reg < 4; ++reg) {
        float g = accg[c][i][reg], u = accu[c][i][reg];
        Hid[(size_t)(rowb + reg) * M + col] = (_Float16)(g / (1.f + expf(-g)) * u);
      }
    }
  }
}

// ---------------- down grouped GEMM -> per-slot rows Yp ----------------
// Same dbuf single-barrier schedule; 32 KB LDS, (256,2).
__global__ __launch_bounds__(256, 2) void k_down(
    const _Float16* __restrict__ Hid, const _Float16* __restrict__ wdT,
    _Float16* __restrict__ Yp, const int* __restrict__ counts) {
  int lin = blockIdx.x;
  int e = lin & 7;
  int r = lin >> 3;
  int nt = r % NT_DN;
  int mt = r / NT_DN;
  int base_e, pc_e, cnt_e;
  expert_base_pc(counts, e, base_e, pc_e, cnt_e);
  if (mt * TM >= pc_e) return;
  int row0 = base_e + mt * TM;
  int d0 = nt * TN;
  __shared__ _Float16 As[2][TM * BK];   // 2 x 8 KB
  __shared__ _Float16 Bs[2][TN * BK];   // 2 x 8 KB
  int tid = threadIdx.x;
  int w = tid >> 6, lane = tid & 63;
  int lrow = lane & 15, quad = lane >> 4;
  int wr = w >> 1, wc = w & 1;
  int sr = lane >> 2;
  int c4 = lane & 3;
  int swc = ((c4 ^ ((sr >> 1) & 3))) * 8;

  const _Float16* wd_e = wdT + (size_t)e * D * M;
  const _Float16* pA[2]; const _Float16* pB[2];
  int loff[2];
  #pragma unroll
  for (int is = 0; is < 2; ++is) {
    int grow = w * 32 + is * 16 + sr;
    pA[is] = Hid  + (size_t)(row0 + grow) * M + swc;
    pB[is] = wd_e + (size_t)(d0   + grow) * M + swc;
    loff[is] = (w * 2 + is) * 1024;
  }

  int swr = (lrow >> 1) & 3;

  floatx4 acc[4][4] = {};

  auto stage = [&](int b) {
    char* a0 = (char*)&As[b][0];
    char* b0 = (char*)&Bs[b][0];
    #pragma unroll
    for (int is = 0; is < 2; ++is) {
      gl_lds16(pA[is], a0 + loff[is]); pA[is] += BK;
      gl_lds16(pB[is], b0 + loff[is]); pB[is] += BK;
    }
  };
  auto compute = [&](int b) {
    int kc = (quad ^ swr) * 8;
    half8 af[4];
    #pragma unroll
    for (int i = 0; i < 4; ++i)
      af[i] = *(const half8*)&As[b][(wr * 64 + i * 16 + lrow) * BK + kc];
    #pragma unroll
    for (int c = 0; c < 4; ++c) {
      half8 bc = *(const half8*)&Bs[b][(wc * 64 + c * 16 + lrow) * BK + kc];
      #pragma unroll
      for (int i = 0; i < 4; ++i)
        acc[c][i] = __builtin_amdgcn_mfma_f32_16x16x32_f16(af[i], bc, acc[c][i], 0, 0, 0);
    }
  };

  stage(0);
  __syncthreads();
  int cur = 0;
  for (int kt = 1; kt < M / BK; ++kt) {
    stage(cur ^ 1);
    compute(cur);
    __syncthreads();
    cur ^= 1;
  }
  compute(cur);

  #pragma unroll
  for (int c = 0; c < 4; ++c) {
    int col = d0 + wc * 64 + c * 16 + lrow;
    #pragma unroll
    for (int i = 0; i < 4; ++i) {
      int rowb = row0 + wr * 64 + i * 16 + quad * 4;
      #pragma unroll
      for (int reg = 0; reg < 4; ++reg)
        Yp[(size_t)(rowb + reg) * D + col] = (_Float16)acc[c][i][reg];
    }
  }
}

// ---------------- combine: y[t] = p0*Yp[r0] + p1*Yp[r1] ----------------
__global__ __launch_bounds__(256) void k_combine(
    const _Float16* __restrict__ Yp, const int* __restrict__ counts,
    const int* __restrict__ t2e, const int* __restrict__ t2pos,
    const float* __restrict__ t2p, float* __restrict__ out) {
  int t = blockIdx.x;
  int e0 = t2e[2 * t], e1 = t2e[2 * t + 1];
  int b = 0, b0 = 0, b1 = 0;
  #pragma unroll
  for (int ee = 0; ee < E; ++ee) {
    if (ee == e0) b0 = b;
    if (ee == e1) b1 = b;
    int c = counts[ee * CSTR];
    b += (c + TM - 1) / TM * TM;
  }
  int r0 = b0 + t2pos[2 * t];
  int r1 = b1 + t2pos[2 * t + 1];
  float p0 = t2p[2 * t], p1 = t2p[2 * t + 1];
  int d = threadIdx.x * 4;
  half4 h0 = *(const half4*)(Yp + (size_t)r0 * D + d);
  half4 h1 = *(const half4*)(Yp + (size_t)r1 * D + d);
  float4 o;
  o.x = p0 * (float)h0.x + p1 * (float)h1.x;
  o.y = p0 * (float)h0.y + p1 * (float)h1.y;
  o.z = p0 * (float)h0.z + p1 * (float)h1.z;
  o.w = p0 * (float)h0.w + p1 * (float)h1.w;
  *(float4*)(out + (size_t)t * D + d) = o;
}

// ---------------- launch ----------------
extern "C" void kernel_launch(void* const* d_in, const int* in_sizes, int n_in,
                              void* d_out, int out_size, void* d_ws, size_t ws_size,
                              hipStream_t stream) {
  const float* x     = (const float*)d_in[0];
  const float* wgate = (const float*)d_in[1];
  const float* w_g   = (const float*)d_in[2];
  const float* w_u   = (const float*)d_in[3];
  const float* w_d   = (const float*)d_in[4];
  float* out = (float*)d_out;
  char* ws = (char*)d_ws;

  if (ws_size < WS_NEED) {
    fprintf(stderr, "kernel_launch: ws_size=%zu < needed %zu\n", ws_size, WS_NEED);
    return;
  }

  int* counts = (int*)(ws + OFF_COUNTS);
  int* t2e    = (int*)(ws + OFF_T2E);
  int* t2pos  = (int*)(ws + OFF_T2POS);
  float* t2p  = (float*)(ws + OFF_T2P);
  int* tlist  = (int*)(ws + OFF_TLIST);
  _Float16* Xh  = (_Float16*)(ws + OFF_XG);   // dense f16 tokens; region reused as Yp
  _Float16* Hid = (_Float16*)(ws + OFF_HID);
  _Float16* wgT = (_Float16*)(ws + OFF_WGT);
  _Float16* wuT = (_Float16*)(ws + OFF_WUT);
  _Float16* wdT = (_Float16*)(ws + OFF_WDT);

  hipMemsetAsync(counts, 0, (size_t)E * CSTR * 4, stream);

  k_prep<<<PREP_GRID, 256, 0, stream>>>(x, wgate, w_g, w_u, w_d, Xh,
                                        wgT, wuT, wdT,
                                        counts, tlist, t2e, t2pos, t2p);
  k_upgate<<<E * MT_MAX * NT_UP, 256, 0, stream>>>(Xh, wgT, wuT, Hid, counts, tlist);
  _Float16* Yp = Xh;   // Xh dead after upgate; reuse region as Yp
  k_down<<<E * MT_MAX * NT_DN, 256, 0, stream>>>(Hid, wdT, Yp, counts);
  k_combine<<<T, 256, 0, stream>>>(Yp, counts, t2e, t2pos, t2p, out);
}

// Round 7
// 297.751 us; speedup vs baseline: 1.3678x; 1.0375x over previous
//
#include <hip/hip_runtime.h>
#include <cstdio>

// ---------------- problem constants ----------------
constexpr int T  = 4096;       // B*S tokens
constexpr int D  = 1024;       // n_embed
constexpr int M  = 1408;       // n_moe_mlp
constexpr int E  = 8;          // experts

constexpr int TM = 128;        // token-rows per tile
constexpr int TN = 128;        // output cols per tile
constexpr int BK = 32;         // K-step (3-buffer pipeline: 3x24KB upgate LDS)
constexpr int RCAP = T * 2 + E * TM;  // 9216 padded row capacity
constexpr int MT_MAX = T / TM; // 32 row-tiles max per expert
constexpr int NT_UP = M / TN;  // 11
constexpr int NT_DN = D / TN;  // 8

constexpr int CSTR = 64;       // per-expert counter stride in ints (256 B)
constexpr int TOKB = 16;       // tokens per router block
constexpr int RTB  = T / TOKB; // 256 router blocks
constexpr int XCV  = (T * D) / 2048;               // 2048 x->fp16 convert blocks
constexpr int TP_PER_W = E * 2816 / 8;             // 2816: E*(R/32)*(C/128) both orients
constexpr int PREP_GRID = RTB + XCV + 3 * TP_PER_W;

typedef _Float16 half8 __attribute__((ext_vector_type(8)));
typedef _Float16 half4 __attribute__((ext_vector_type(4)));
typedef float    floatx4 __attribute__((ext_vector_type(4)));

// counted vmcnt waits (T4): never drain to 0 in the main loop.
#define VMW12() asm volatile("s_waitcnt vmcnt(12)" ::: "memory")
#define VMW8()  asm volatile("s_waitcnt vmcnt(8)"  ::: "memory")
#define VMW6()  asm volatile("s_waitcnt vmcnt(6)"  ::: "memory")
#define VMW4()  asm volatile("s_waitcnt vmcnt(4)"  ::: "memory")
#define VMW0()  asm volatile("s_waitcnt vmcnt(0)"  ::: "memory")

// ---------------- ws layout (bytes) ----------------
constexpr size_t OFF_COUNTS = 0;                               // E*CSTR ints
constexpr size_t OFF_BASE   = (size_t)E * CSTR * 4;
constexpr size_t OFF_PC     = OFF_BASE + 64;
constexpr size_t OFF_TOTAL  = OFF_PC + 64;
constexpr size_t OFF_T2E    = OFF_TOTAL + 64;                  // 2T ints
constexpr size_t OFF_T2POS  = OFF_T2E   + (size_t)2 * T * 4;
constexpr size_t OFF_T2P    = OFF_T2POS + (size_t)2 * T * 4;
constexpr size_t OFF_TLIST  = OFF_T2P   + (size_t)2 * T * 4;   // E*T ints
constexpr size_t OFF_XG     = OFF_TLIST + (size_t)E * T * 4;   // Xh (T x D f16) then Yp
constexpr size_t OFF_HID    = OFF_XG  + (size_t)RCAP * D * 2;  // RCAP x M fp16
constexpr size_t OFF_WGT    = OFF_HID + (size_t)RCAP * M * 2;  // E x M x D fp16
constexpr size_t OFF_WUT    = OFF_WGT + (size_t)E * M * D * 2;
constexpr size_t OFF_WDT    = OFF_WUT + (size_t)E * M * D * 2; // E x D x M fp16
constexpr size_t WS_NEED    = OFF_WDT + (size_t)E * D * M * 2;

// async global->LDS, 16B per lane. LDS dest = wave-uniform base + lane*16;
// GLOBAL source is per-lane (enables gather + source-side swizzle).
__device__ __forceinline__ void gl_lds16(const void* g, void* l) {
  __builtin_amdgcn_global_load_lds(
      (const __attribute__((address_space(1))) unsigned int*)g,
      (__attribute__((address_space(3))) unsigned int*)l, 16, 0, 0);
}

// 8-expert padded prefix via uniform scalar loads.
__device__ __forceinline__ void expert_base_pc(const int* __restrict__ counts,
                                               int e, int& base_e, int& pc_e,
                                               int& cnt_e) {
  int b = 0; base_e = 0; pc_e = 0; cnt_e = 0;
  #pragma unroll
  for (int ee = 0; ee < E; ++ee) {
    int c = counts[ee * CSTR];
    int p = (c + TM - 1) / TM * TM;
    if (ee == e) { base_e = b; pc_e = p; cnt_e = c; }
    b += p;
  }
}

// ---------------- fused prep: router + x->f16 convert + weight transposes ------
__global__ __launch_bounds__(256) void k_prep(
    const float* __restrict__ x, const float* __restrict__ wgate,
    const float* __restrict__ w_g, const float* __restrict__ w_u,
    const float* __restrict__ w_d,
    _Float16* __restrict__ Xh,
    _Float16* __restrict__ wgT, _Float16* __restrict__ wuT, _Float16* __restrict__ wdT,
    int* __restrict__ counts, int* __restrict__ tlist,
    int* __restrict__ t2e, int* __restrict__ t2pos, float* __restrict__ t2p) {
  __shared__ float tile[4][32][33];
  __shared__ int   s_cnt[E];
  __shared__ int   s_base[E];
  __shared__ int   s_e[2 * TOKB];
  __shared__ int   s_pos[2 * TOKB];
  __shared__ float s_p[2 * TOKB];
  int bid = blockIdx.x;

  if (bid < RTB) {
    // ---- router for tokens [bid*TOKB, +TOKB) ----
    int wv = threadIdx.x >> 6, lane = threadIdx.x & 63;
    if (threadIdx.x < E) s_cnt[threadIdx.x] = 0;
    __syncthreads();
    for (int j = 0; j < TOKB / 4; ++j) {
      int tl = wv * (TOKB / 4) + j;
      int t  = bid * TOKB + tl;
      const float* xr = x + (size_t)t * D;
      float acc[E] = {0.f,0.f,0.f,0.f,0.f,0.f,0.f,0.f};
      #pragma unroll
      for (int i = 0; i < D / 64; ++i) {
        int d = i * 64 + lane;
        float xv = xr[d];
        const float4* wr2 = (const float4*)(wgate + (size_t)d * E);
        float4 w0 = wr2[0], w1 = wr2[1];
        acc[0] += xv * w0.x; acc[1] += xv * w0.y; acc[2] += xv * w0.z; acc[3] += xv * w0.w;
        acc[4] += xv * w1.x; acc[5] += xv * w1.y; acc[6] += xv * w1.z; acc[7] += xv * w1.w;
      }
      #pragma unroll
      for (int e = 0; e < E; ++e) {
        #pragma unroll
        for (int off = 32; off; off >>= 1) acc[e] += __shfl_xor(acc[e], off, 64);
      }
      if (lane == 0) {
        int i0 = 0; float s0 = acc[0];
        #pragma unroll
        for (int e = 1; e < E; ++e) if (acc[e] > s0) { s0 = acc[e]; i0 = e; }
        int i1 = -1; float s1 = -1e30f;
        #pragma unroll
        for (int e = 0; e < E; ++e) if (e != i0 && acc[e] > s1) { s1 = acc[e]; i1 = e; }
        float p0 = 1.f / (1.f + expf(s1 - s0));
        float p1 = 1.f - p0;
        int q0 = atomicAdd(&s_cnt[i0], 1);
        int q1 = atomicAdd(&s_cnt[i1], 1);
        s_e[2 * tl]     = i0; s_pos[2 * tl]     = q0; s_p[2 * tl]     = p0;
        s_e[2 * tl + 1] = i1; s_pos[2 * tl + 1] = q1; s_p[2 * tl + 1] = p1;
      }
    }
    __syncthreads();
    if (threadIdx.x < E)
      s_base[threadIdx.x] = atomicAdd(&counts[threadIdx.x * CSTR], s_cnt[threadIdx.x]);
    __syncthreads();
    if (threadIdx.x < 2 * TOKB) {
      int sl = threadIdx.x;
      int e = s_e[sl];
      int pos = s_base[e] + s_pos[sl];
      int t = bid * TOKB + (sl >> 1);
      tlist[e * T + pos] = t;
      t2e[2 * t + (sl & 1)]   = e;
      t2pos[2 * t + (sl & 1)] = pos;
      t2p[2 * t + (sl & 1)]   = s_p[sl];
    }
    return;
  }

  if (bid < RTB + XCV) {
    // ---- x (f32) -> Xh (f16), dense token-major ----
    size_t base = (size_t)(bid - RTB) * 2048 + threadIdx.x * 8;
    float4 v0 = *(const float4*)(x + base);
    float4 v1 = *(const float4*)(x + base + 4);
    half8 h;
    h[0] = (_Float16)v0.x; h[1] = (_Float16)v0.y;
    h[2] = (_Float16)v0.z; h[3] = (_Float16)v0.w;
    h[4] = (_Float16)v1.x; h[5] = (_Float16)v1.y;
    h[6] = (_Float16)v1.z; h[7] = (_Float16)v1.w;
    *(half8*)(Xh + base) = h;
    return;
  }

  // ---- transpose-convert [E][R][C] f32 -> [E][C][R] f16, 32x128 strip/block ----
  int i = bid - RTB - XCV;
  int which = i / TP_PER_W;
  int j = i - which * TP_PER_W;
  const float* src; _Float16* dst; int Rr, Cc;
  if (which == 0)      { src = w_g; dst = wgT; Rr = D; Cc = M; }
  else if (which == 1) { src = w_u; dst = wuT; Rr = D; Cc = M; }
  else                 { src = w_d; dst = wdT; Rr = M; Cc = D; }
  int ctn = Cc / 128, rtn = Rr / 32;
  int e   = j / (ctn * rtn);
  int rem = j - e * (ctn * rtn);
  int rt = rem / ctn, ct = rem - rt * ctn;
  int tr  = threadIdx.x >> 3;
  int tc4 = (threadIdx.x & 7) * 4;
  const float* s = src + ((size_t)e * Rr + rt * 32 + tr) * Cc + ct * 128 + tc4;
  float4 v[4];
  #pragma unroll
  for (int q = 0; q < 4; ++q) v[q] = *(const float4*)(s + q * 32);
  #pragma unroll
  for (int q = 0; q < 4; ++q) {
    tile[q][tr][tc4 + 0] = v[q].x; tile[q][tr][tc4 + 1] = v[q].y;
    tile[q][tr][tc4 + 2] = v[q].z; tile[q][tr][tc4 + 3] = v[q].w;
  }
  __syncthreads();
  #pragma unroll
  for (int q = 0; q < 4; ++q) {
    union { _Float16 h[4]; ushort4 u; } o;
    #pragma unroll
    for (int p = 0; p < 4; ++p) o.h[p] = (_Float16)tile[q][tc4 + p][tr];
    *(ushort4*)(dst + ((size_t)e * Cc + ct * 128 + q * 32 + tr) * Rr + rt * 32 + tc4) = o.u;
  }
}

// ---------------- fused gate+up grouped GEMM + SiLU ----------------
// 3-buffer pipeline with COUNTED vmcnt + RAW s_barrier (T4, m218): iteration k
// stages step k+2, waits vmcnt(12) (only step-k's 6 loads must land), raw
// barrier (no drain!), compute, raw barrier. Loads stay in flight across
// barriers; each gets ~2 compute phases to cover HBM latency. Buffer hazard
// fenced by trailing barrier (stage(k+2) hits buf[(k-1)%3], last read before
// that barrier). Gather-from-Xh + both-sides swizzle as round 6 (verified).
__global__ __launch_bounds__(256, 2) void k_upgate(
    const _Float16* __restrict__ Xh, const _Float16* __restrict__ wgT,
    const _Float16* __restrict__ wuT, _Float16* __restrict__ Hid,
    const int* __restrict__ counts, const int* __restrict__ tlist) {
  int lin = blockIdx.x;
  int e = lin & 7;
  int r = lin >> 3;
  int nt = r % NT_UP;
  int mt = r / NT_UP;
  int base_e, pc_e, cnt_e;
  expert_base_pc(counts, e, base_e, pc_e, cnt_e);
  if (mt * TM >= pc_e) return;
  int row0 = base_e + mt * TM;
  int n0 = nt * TN;
  __shared__ _Float16 As[3][TM * BK];   // 3 x 8 KB
  __shared__ _Float16 Bg[3][TN * BK];   // 3 x 8 KB
  __shared__ _Float16 Bu[3][TN * BK];   // 3 x 8 KB
  int tid = threadIdx.x;
  int w = tid >> 6, lane = tid & 63;
  int lrow = lane & 15, quad = lane >> 4;
  int wr = w >> 1, wc = w & 1;
  int sr = lane >> 2;                         // staging row within 16-row group
  int c4 = lane & 3;                          // staging chunk
  int swc = ((c4 ^ ((sr >> 1) & 3))) * 8;     // pre-swizzled source chunk (halves)

  const _Float16* wg_e = wgT + (size_t)e * M * D;
  const _Float16* wu_e = wuT + (size_t)e * M * D;
  const _Float16* pA[2]; const _Float16* pG[2]; const _Float16* pU[2];
  int loff[2];
  #pragma unroll
  for (int is = 0; is < 2; ++is) {
    int grow = w * 32 + is * 16 + sr;         // tile row 0..127
    int local = mt * TM + grow;
    int trow = (local < cnt_e) ? tlist[e * T + local] : 0;  // pad-safe gather
    pA[is] = Xh   + (size_t)trow * D + swc;
    pG[is] = wg_e + (size_t)(n0 + grow) * D + swc;
    pU[is] = wu_e + (size_t)(n0 + grow) * D + swc;
    loff[is] = (w * 2 + is) * 1024;
  }

  int swr = (lrow >> 1) & 3;                  // read-side swizzle

  floatx4 accg[4][4] = {};   // [c][i]
  floatx4 accu[4][4] = {};

  auto stage = [&](int b) {
    char* a0 = (char*)&As[b][0];
    char* g0 = (char*)&Bg[b][0];
    char* u0 = (char*)&Bu[b][0];
    #pragma unroll
    for (int is = 0; is < 2; ++is) {
      gl_lds16(pA[is], a0 + loff[is]); pA[is] += BK;
      gl_lds16(pG[is], g0 + loff[is]); pG[is] += BK;
      gl_lds16(pU[is], u0 + loff[is]); pU[is] += BK;
    }
  };
  auto compute = [&](int b) {
    int kc = (quad ^ swr) * 8;
    half8 af[4];
    #pragma unroll
    for (int i = 0; i < 4; ++i)
      af[i] = *(const half8*)&As[b][(wr * 64 + i * 16 + lrow) * BK + kc];
    #pragma unroll
    for (int c = 0; c < 4; ++c) {
      int bo = (wc * 64 + c * 16 + lrow) * BK + kc;
      half8 bgc = *(const half8*)&Bg[b][bo];
      half8 buc = *(const half8*)&Bu[b][bo];
      #pragma unroll
      for (int i = 0; i < 4; ++i) {
        accg[c][i] = __builtin_amdgcn_mfma_f32_16x16x32_f16(af[i], bgc, accg[c][i], 0, 0, 0);
        accu[c][i] = __builtin_amdgcn_mfma_f32_16x16x32_f16(af[i], buc, accu[c][i], 0, 0, 0);
      }
    }
  };

  constexpr int NTK = D / BK;   // 32
  stage(0); stage(1);
  for (int k = 0; k < NTK; ++k) {
    if (k + 2 < NTK) {
      stage((k + 2) % 3);
      VMW12();
    } else if (k + 1 < NTK) {
      VMW6();
    } else {
      VMW0();
    }
    __builtin_amdgcn_sched_barrier(0);
    __builtin_amdgcn_s_barrier();
    compute(k % 3);
    __builtin_amdgcn_s_barrier();
  }

  #pragma unroll
  for (int c = 0; c < 4; ++c) {
    int col = n0 + wc * 64 + c * 16 + lrow;
    #pragma unroll
    for (int i = 0; i < 4; ++i) {
      int rowb = row0 + wr * 64 + i * 16 + quad * 4;
      #pragma unroll
      for (int reg = 0; reg < 4; ++reg) {
        float g = accg[c][i][reg], u = accu[c][i][reg];
        Hid[(size_t)(rowb + reg) * M + col] = (_Float16)(g / (1.f + expf(-g)) * u);
      }
    }
  }
}

// ---------------- down grouped GEMM -> per-slot rows Yp ----------------
// Same 3-buffer counted-vmcnt pipeline; 4 loads/stage -> vmcnt(8)/(4)/(0).
__global__ __launch_bounds__(256, 2) void k_down(
    const _Float16* __restrict__ Hid, const _Float16* __restrict__ wdT,
    _Float16* __restrict__ Yp, const int* __restrict__ counts) {
  int lin = blockIdx.x;
  int e = lin & 7;
  int r = lin >> 3;
  int nt = r % NT_DN;
  int mt = r / NT_DN;
  int base_e, pc_e, cnt_e;
  expert_base_pc(counts, e, base_e, pc_e, cnt_e);
  if (mt * TM >= pc_e) return;
  int row0 = base_e + mt * TM;
  int d0 = nt * TN;
  __shared__ _Float16 As[3][TM * BK];   // 3 x 8 KB
  __shared__ _Float16 Bs[3][TN * BK];   // 3 x 8 KB
  int tid = threadIdx.x;
  int w = tid >> 6, lane = tid & 63;
  int lrow = lane & 15, quad = lane >> 4;
  int wr = w >> 1, wc = w & 1;
  int sr = lane >> 2;
  int c4 = lane & 3;
  int swc = ((c4 ^ ((sr >> 1) & 3))) * 8;

  const _Float16* wd_e = wdT + (size_t)e * D * M;
  const _Float16* pA[2]; const _Float16* pB[2];
  int loff[2];
  #pragma unroll
  for (int is = 0; is < 2; ++is) {
    int grow = w * 32 + is * 16 + sr;
    pA[is] = Hid  + (size_t)(row0 + grow) * M + swc;
    pB[is] = wd_e + (size_t)(d0   + grow) * M + swc;
    loff[is] = (w * 2 + is) * 1024;
  }

  int swr = (lrow >> 1) & 3;

  floatx4 acc[4][4] = {};

  auto stage = [&](int b) {
    char* a0 = (char*)&As[b][0];
    char* b0 = (char*)&Bs[b][0];
    #pragma unroll
    for (int is = 0; is < 2; ++is) {
      gl_lds16(pA[is], a0 + loff[is]); pA[is] += BK;
      gl_lds16(pB[is], b0 + loff[is]); pB[is] += BK;
    }
  };
  auto compute = [&](int b) {
    int kc = (quad ^ swr) * 8;
    half8 af[4];
    #pragma unroll
    for (int i = 0; i < 4; ++i)
      af[i] = *(const half8*)&As[b][(wr * 64 + i * 16 + lrow) * BK + kc];
    #pragma unroll
    for (int c = 0; c < 4; ++c) {
      half8 bc = *(const half8*)&Bs[b][(wc * 64 + c * 16 + lrow) * BK + kc];
      #pragma unroll
      for (int i = 0; i < 4; ++i)
        acc[c][i] = __builtin_amdgcn_mfma_f32_16x16x32_f16(af[i], bc, acc[c][i], 0, 0, 0);
    }
  };

  constexpr int NTK = M / BK;   // 44
  stage(0); stage(1);
  for (int k = 0; k < NTK; ++k) {
    if (k + 2 < NTK) {
      stage((k + 2) % 3);
      VMW8();
    } else if (k + 1 < NTK) {
      VMW4();
    } else {
      VMW0();
    }
    __builtin_amdgcn_sched_barrier(0);
    __builtin_amdgcn_s_barrier();
    compute(k % 3);
    __builtin_amdgcn_s_barrier();
  }

  #pragma unroll
  for (int c = 0; c < 4; ++c) {
    int col = d0 + wc * 64 + c * 16 + lrow;
    #pragma unroll
    for (int i = 0; i < 4; ++i) {
      int rowb = row0 + wr * 64 + i * 16 + quad * 4;
      #pragma unroll
      for (int reg = 0; reg < 4; ++reg)
        Yp[(size_t)(rowb + reg) * D + col] = (_Float16)acc[c][i][reg];
    }
  }
}

// ---------------- combine: y[t] = p0*Yp[r0] + p1*Yp[r1] ----------------
__global__ __launch_bounds__(256) void k_combine(
    const _Float16* __restrict__ Yp, const int* __restrict__ counts,
    const int* __restrict__ t2e, const int* __restrict__ t2pos,
    const float* __restrict__ t2p, float* __restrict__ out) {
  int t = blockIdx.x;
  int e0 = t2e[2 * t], e1 = t2e[2 * t + 1];
  int b = 0, b0 = 0, b1 = 0;
  #pragma unroll
  for (int ee = 0; ee < E; ++ee) {
    if (ee == e0) b0 = b;
    if (ee == e1) b1 = b;
    int c = counts[ee * CSTR];
    b += (c + TM - 1) / TM * TM;
  }
  int r0 = b0 + t2pos[2 * t];
  int r1 = b1 + t2pos[2 * t + 1];
  float p0 = t2p[2 * t], p1 = t2p[2 * t + 1];
  int d = threadIdx.x * 4;
  half4 h0 = *(const half4*)(Yp + (size_t)r0 * D + d);
  half4 h1 = *(const half4*)(Yp + (size_t)r1 * D + d);
  float4 o;
  o.x = p0 * (float)h0.x + p1 * (float)h1.x;
  o.y = p0 * (float)h0.y + p1 * (float)h1.y;
  o.z = p0 * (float)h0.z + p1 * (float)h1.z;
  o.w = p0 * (float)h0.w + p1 * (float)h1.w;
  *(float4*)(out + (size_t)t * D + d) = o;
}

// ---------------- launch ----------------
extern "C" void kernel_launch(void* const* d_in, const int* in_sizes, int n_in,
                              void* d_out, int out_size, void* d_ws, size_t ws_size,
                              hipStream_t stream) {
  const float* x     = (const float*)d_in[0];
  const float* wgate = (const float*)d_in[1];
  const float* w_g   = (const float*)d_in[2];
  const float* w_u   = (const float*)d_in[3];
  const float* w_d   = (const float*)d_in[4];
  float* out = (float*)d_out;
  char* ws = (char*)d_ws;

  if (ws_size < WS_NEED) {
    fprintf(stderr, "kernel_launch: ws_size=%zu < needed %zu\n", ws_size, WS_NEED);
    return;
  }

  int* counts = (int*)(ws + OFF_COUNTS);
  int* t2e    = (int*)(ws + OFF_T2E);
  int* t2pos  = (int*)(ws + OFF_T2POS);
  float* t2p  = (float*)(ws + OFF_T2P);
  int* tlist  = (int*)(ws + OFF_TLIST);
  _Float16* Xh  = (_Float16*)(ws + OFF_XG);   // dense f16 tokens; region reused as Yp
  _Float16* Hid = (_Float16*)(ws + OFF_HID);
  _Float16* wgT = (_Float16*)(ws + OFF_WGT);
  _Float16* wuT = (_Float16*)(ws + OFF_WUT);
  _Float16* wdT = (_Float16*)(ws + OFF_WDT);

  hipMemsetAsync(counts, 0, (size_t)E * CSTR * 4, stream);

  k_prep<<<PREP_GRID, 256, 0, stream>>>(x, wgate, w_g, w_u, w_d, Xh,
                                        wgT, wuT, wdT,
                                        counts, tlist, t2e, t2pos, t2p);
  k_upgate<<<E * MT_MAX * NT_UP, 256, 0, stream>>>(Xh, wgT, wuT, Hid, counts, tlist);
  _Float16* Yp = Xh;   // Xh dead after upgate; reuse region as Yp
  k_down<<<E * MT_MAX * NT_DN, 256, 0, stream>>>(Hid, wdT, Yp, counts);
  k_combine<<<T, 256, 0, stream>>>(Yp, counts, t2e, t2pos, t2p, out);
}

// Round 8
// 288.487 us; speedup vs baseline: 1.4117x; 1.0321x over previous
//
#include <hip/hip_runtime.h>
#include <cstdio>

// ---------------- problem constants ----------------
constexpr int T  = 4096;       // B*S tokens
constexpr int D  = 1024;       // n_embed
constexpr int M  = 1408;       // n_moe_mlp
constexpr int E  = 8;          // experts

constexpr int TM = 128;        // token-rows per tile
constexpr int TN = 128;        // output cols per tile
constexpr int BK = 32;         // K-step (3-buffer pipeline)
constexpr int RCAP = T * 2 + E * TM;  // 9216 padded row capacity
constexpr int MT_MAX = T / TM; // 32 row-tiles max per expert
constexpr int NT_UP = M / TN;  // 11
constexpr int NT_DN = D / TN;  // 8

constexpr int CSTR = 64;       // per-expert counter stride in ints (256 B)
constexpr int TOKB = 16;       // tokens per router block
constexpr int RTB  = T / TOKB; // 256 router blocks
constexpr int XCV  = (T * D) / 2048;            // 2048 x->fp16 convert blocks
constexpr int TPW  = E * (D / 64) * (M / 64);   // 2816 transpose tiles per weight
constexpr int PREP_GRID = RTB + XCV + 2 * TPW;  // router + convert + wg,wu transposes
constexpr int NGEMM_UP  = E * MT_MAX * NT_UP;   // 2816
constexpr int UPG_GRID  = NGEMM_UP + TPW;       // + wd transpose blocks (fill slack)

typedef _Float16 half8 __attribute__((ext_vector_type(8)));
typedef _Float16 half4 __attribute__((ext_vector_type(4)));
typedef float    floatx4 __attribute__((ext_vector_type(4)));

// counted vmcnt waits (T4): never drain to 0 in the main loop.
#define VMW12() asm volatile("s_waitcnt vmcnt(12)" ::: "memory")
#define VMW8()  asm volatile("s_waitcnt vmcnt(8)"  ::: "memory")
#define VMW6()  asm volatile("s_waitcnt vmcnt(6)"  ::: "memory")
#define VMW4()  asm volatile("s_waitcnt vmcnt(4)"  ::: "memory")
#define VMW0()  asm volatile("s_waitcnt vmcnt(0)"  ::: "memory")

// ---------------- ws layout (bytes) ----------------
constexpr size_t OFF_COUNTS = 0;                               // E*CSTR ints
constexpr size_t OFF_BASE   = (size_t)E * CSTR * 4;
constexpr size_t OFF_PC     = OFF_BASE + 64;
constexpr size_t OFF_TOTAL  = OFF_PC + 64;
constexpr size_t OFF_T2E    = OFF_TOTAL + 64;                  // 2T ints
constexpr size_t OFF_T2POS  = OFF_T2E   + (size_t)2 * T * 4;
constexpr size_t OFF_T2P    = OFF_T2POS + (size_t)2 * T * 4;
constexpr size_t OFF_TLIST  = OFF_T2P   + (size_t)2 * T * 4;   // E*T ints
constexpr size_t OFF_XG     = OFF_TLIST + (size_t)E * T * 4;   // Xh (T x D f16) then Yp
constexpr size_t OFF_HID    = OFF_XG  + (size_t)RCAP * D * 2;  // RCAP x M fp16
constexpr size_t OFF_WGT    = OFF_HID + (size_t)RCAP * M * 2;  // E x M x D fp16
constexpr size_t OFF_WUT    = OFF_WGT + (size_t)E * M * D * 2;
constexpr size_t OFF_WDT    = OFF_WUT + (size_t)E * M * D * 2; // E x D x M fp16
constexpr size_t WS_NEED    = OFF_WDT + (size_t)E * D * M * 2;

// async global->LDS, 16B per lane. LDS dest = wave-uniform base + lane*16;
// GLOBAL source is per-lane (enables gather + source-side swizzle).
__device__ __forceinline__ void gl_lds16(const void* g, void* l) {
  __builtin_amdgcn_global_load_lds(
      (const __attribute__((address_space(1))) unsigned int*)g,
      (__attribute__((address_space(3))) unsigned int*)l, 16, 0, 0);
}

// 8-expert padded prefix via uniform scalar loads.
__device__ __forceinline__ void expert_base_pc(const int* __restrict__ counts,
                                               int e, int& base_e, int& pc_e,
                                               int& cnt_e) {
  int b = 0; base_e = 0; pc_e = 0; cnt_e = 0;
  #pragma unroll
  for (int ee = 0; ee < E; ++ee) {
    int c = counts[ee * CSTR];
    int p = (c + TM - 1) / TM * TM;
    if (ee == e) { base_e = b; pc_e = p; cnt_e = c; }
    b += p;
  }
}

// ---------------- 64x64 f32->f16 transpose tile -------------------------------
// src [E][Rr][Cc] f32 -> dst [E][Cc][Rr] f16.  Reads: 256B-contiguous per
// 4 threads.  Writes: 8 lanes x half8(16B) = 128B-contiguous segments (the
// old 32-wide version wrote 64B segments -> half write efficiency).
// LDS [64][69] f32: row stride 69 => transposed-read bank spread <=2-way.
__device__ __forceinline__ void transpose64(
    const float* __restrict__ src, _Float16* __restrict__ dst,
    int Rr, int Cc, int j, float (*tile)[69]) {
  int ctn = Cc >> 6, rtn = Rr >> 6;
  int e   = j / (ctn * rtn);
  int rem = j - e * (ctn * rtn);
  int rt = rem / ctn, ct = rem - rt * ctn;
  int t = threadIdx.x;
  int lr = t >> 2;            // 0..63 source row
  int lc = (t & 3) * 16;      // 16-float chunk
  const float* s = src + ((size_t)e * Rr + rt * 64 + lr) * Cc + ct * 64 + lc;
  float4 v0 = *(const float4*)(s + 0);
  float4 v1 = *(const float4*)(s + 4);
  float4 v2 = *(const float4*)(s + 8);
  float4 v3 = *(const float4*)(s + 12);
  float* tr = &tile[lr][lc];
  tr[0]  = v0.x; tr[1]  = v0.y; tr[2]  = v0.z; tr[3]  = v0.w;
  tr[4]  = v1.x; tr[5]  = v1.y; tr[6]  = v1.z; tr[7]  = v1.w;
  tr[8]  = v2.x; tr[9]  = v2.y; tr[10] = v2.z; tr[11] = v2.w;
  tr[12] = v3.x; tr[13] = v3.y; tr[14] = v3.z; tr[15] = v3.w;
  __syncthreads();
  #pragma unroll
  for (int rep = 0; rep < 2; ++rep) {
    int s2 = t + rep * 256;
    int oc = s2 >> 3;         // 0..63 output row (= source col)
    int sl = s2 & 7;          // 16B segment within output row
    half8 o;
    #pragma unroll
    for (int q = 0; q < 8; ++q) o[q] = (_Float16)tile[sl * 8 + q][oc];
    *(half8*)(dst + ((size_t)e * Cc + ct * 64 + oc) * Rr + rt * 64 + sl * 8) = o;
  }
}

// ---------------- fused prep: router + x->f16 convert + wg/wu transposes ------
__global__ __launch_bounds__(256) void k_prep(
    const float* __restrict__ x, const float* __restrict__ wgate,
    const float* __restrict__ w_g, const float* __restrict__ w_u,
    _Float16* __restrict__ Xh,
    _Float16* __restrict__ wgT, _Float16* __restrict__ wuT,
    int* __restrict__ counts, int* __restrict__ tlist,
    int* __restrict__ t2e, int* __restrict__ t2pos, float* __restrict__ t2p) {
  __shared__ float tile[64][69];
  __shared__ int   s_cnt[E];
  __shared__ int   s_base[E];
  __shared__ int   s_e[2 * TOKB];
  __shared__ int   s_pos[2 * TOKB];
  __shared__ float s_p[2 * TOKB];
  int bid = blockIdx.x;

  if (bid < RTB) {
    // ---- router for tokens [bid*TOKB, +TOKB) ----
    int wv = threadIdx.x >> 6, lane = threadIdx.x & 63;
    if (threadIdx.x < E) s_cnt[threadIdx.x] = 0;
    __syncthreads();
    for (int j = 0; j < TOKB / 4; ++j) {
      int tl = wv * (TOKB / 4) + j;
      int t  = bid * TOKB + tl;
      const float* xr = x + (size_t)t * D;
      float acc[E] = {0.f,0.f,0.f,0.f,0.f,0.f,0.f,0.f};
      #pragma unroll
      for (int i = 0; i < D / 64; ++i) {
        int d = i * 64 + lane;
        float xv = xr[d];
        const float4* wr2 = (const float4*)(wgate + (size_t)d * E);
        float4 w0 = wr2[0], w1 = wr2[1];
        acc[0] += xv * w0.x; acc[1] += xv * w0.y; acc[2] += xv * w0.z; acc[3] += xv * w0.w;
        acc[4] += xv * w1.x; acc[5] += xv * w1.y; acc[6] += xv * w1.z; acc[7] += xv * w1.w;
      }
      #pragma unroll
      for (int e = 0; e < E; ++e) {
        #pragma unroll
        for (int off = 32; off; off >>= 1) acc[e] += __shfl_xor(acc[e], off, 64);
      }
      if (lane == 0) {
        int i0 = 0; float s0 = acc[0];
        #pragma unroll
        for (int e = 1; e < E; ++e) if (acc[e] > s0) { s0 = acc[e]; i0 = e; }
        int i1 = -1; float s1 = -1e30f;
        #pragma unroll
        for (int e = 0; e < E; ++e) if (e != i0 && acc[e] > s1) { s1 = acc[e]; i1 = e; }
        float p0 = 1.f / (1.f + expf(s1 - s0));
        float p1 = 1.f - p0;
        int q0 = atomicAdd(&s_cnt[i0], 1);
        int q1 = atomicAdd(&s_cnt[i1], 1);
        s_e[2 * tl]     = i0; s_pos[2 * tl]     = q0; s_p[2 * tl]     = p0;
        s_e[2 * tl + 1] = i1; s_pos[2 * tl + 1] = q1; s_p[2 * tl + 1] = p1;
      }
    }
    __syncthreads();
    if (threadIdx.x < E)
      s_base[threadIdx.x] = atomicAdd(&counts[threadIdx.x * CSTR], s_cnt[threadIdx.x]);
    __syncthreads();
    if (threadIdx.x < 2 * TOKB) {
      int sl = threadIdx.x;
      int e = s_e[sl];
      int pos = s_base[e] + s_pos[sl];
      int t = bid * TOKB + (sl >> 1);
      tlist[e * T + pos] = t;
      t2e[2 * t + (sl & 1)]   = e;
      t2pos[2 * t + (sl & 1)] = pos;
      t2p[2 * t + (sl & 1)]   = s_p[sl];
    }
    return;
  }

  if (bid < RTB + XCV) {
    // ---- x (f32) -> Xh (f16), dense token-major ----
    size_t base = (size_t)(bid - RTB) * 2048 + threadIdx.x * 8;
    float4 v0 = *(const float4*)(x + base);
    float4 v1 = *(const float4*)(x + base + 4);
    half8 h;
    h[0] = (_Float16)v0.x; h[1] = (_Float16)v0.y;
    h[2] = (_Float16)v0.z; h[3] = (_Float16)v0.w;
    h[4] = (_Float16)v1.x; h[5] = (_Float16)v1.y;
    h[6] = (_Float16)v1.z; h[7] = (_Float16)v1.w;
    *(half8*)(Xh + base) = h;
    return;
  }

  // ---- wg / wu transpose-convert ----
  int i = bid - RTB - XCV;
  if (i < TPW) transpose64(w_g, wgT, D, M, i, tile);
  else         transpose64(w_u, wuT, D, M, i - TPW, tile);
}

// ---------------- fused gate+up grouped GEMM + SiLU (+ wd transpose blocks) ---
// GEMM: 3-buffer counted-vmcnt pipeline (round-7, verified).  Blocks with
// bid >= NGEMM_UP instead transpose w_d -> wdT, filling this dispatch's idle
// CU slots / memory BW (upgate is latency-bound at 12% HBM); k_down's wdT
// dependency is preserved because it launches after this dispatch completes.
__global__ __launch_bounds__(256, 2) void k_upgate(
    const _Float16* __restrict__ Xh, const _Float16* __restrict__ wgT,
    const _Float16* __restrict__ wuT, _Float16* __restrict__ Hid,
    const int* __restrict__ counts, const int* __restrict__ tlist,
    const float* __restrict__ w_d, _Float16* __restrict__ wdT) {
  __shared__ _Float16 As[3][TM * BK];   // 3 x 8 KB
  __shared__ _Float16 Bg[3][TN * BK];   // 3 x 8 KB
  __shared__ _Float16 Bu[3][TN * BK];   // 3 x 8 KB
  int lin = blockIdx.x;
  if (lin >= NGEMM_UP) {
    float (*tile)[69] = reinterpret_cast<float (*)[69]>(&As[0][0]);  // 17.7KB < 24KB
    transpose64(w_d, wdT, M, D, lin - NGEMM_UP, tile);
    return;
  }
  int e = lin & 7;
  int r = lin >> 3;
  int nt = r % NT_UP;
  int mt = r / NT_UP;
  int base_e, pc_e, cnt_e;
  expert_base_pc(counts, e, base_e, pc_e, cnt_e);
  if (mt * TM >= pc_e) return;
  int row0 = base_e + mt * TM;
  int n0 = nt * TN;
  int tid = threadIdx.x;
  int w = tid >> 6, lane = tid & 63;
  int lrow = lane & 15, quad = lane >> 4;
  int wr = w >> 1, wc = w & 1;
  int sr = lane >> 2;                         // staging row within 16-row group
  int c4 = lane & 3;                          // staging chunk
  int swc = ((c4 ^ ((sr >> 1) & 3))) * 8;     // pre-swizzled source chunk (halves)

  const _Float16* wg_e = wgT + (size_t)e * M * D;
  const _Float16* wu_e = wuT + (size_t)e * M * D;
  const _Float16* pA[2]; const _Float16* pG[2]; const _Float16* pU[2];
  int loff[2];
  #pragma unroll
  for (int is = 0; is < 2; ++is) {
    int grow = w * 32 + is * 16 + sr;         // tile row 0..127
    int local = mt * TM + grow;
    int trow = (local < cnt_e) ? tlist[e * T + local] : 0;  // pad-safe gather
    pA[is] = Xh   + (size_t)trow * D + swc;
    pG[is] = wg_e + (size_t)(n0 + grow) * D + swc;
    pU[is] = wu_e + (size_t)(n0 + grow) * D + swc;
    loff[is] = (w * 2 + is) * 1024;
  }

  int swr = (lrow >> 1) & 3;                  // read-side swizzle

  floatx4 accg[4][4] = {};   // [c][i]
  floatx4 accu[4][4] = {};

  auto stage = [&](int b) {
    char* a0 = (char*)&As[b][0];
    char* g0 = (char*)&Bg[b][0];
    char* u0 = (char*)&Bu[b][0];
    #pragma unroll
    for (int is = 0; is < 2; ++is) {
      gl_lds16(pA[is], a0 + loff[is]); pA[is] += BK;
      gl_lds16(pG[is], g0 + loff[is]); pG[is] += BK;
      gl_lds16(pU[is], u0 + loff[is]); pU[is] += BK;
    }
  };
  auto compute = [&](int b) {
    int kc = (quad ^ swr) * 8;
    half8 af[4];
    #pragma unroll
    for (int i = 0; i < 4; ++i)
      af[i] = *(const half8*)&As[b][(wr * 64 + i * 16 + lrow) * BK + kc];
    #pragma unroll
    for (int c = 0; c < 4; ++c) {
      int bo = (wc * 64 + c * 16 + lrow) * BK + kc;
      half8 bgc = *(const half8*)&Bg[b][bo];
      half8 buc = *(const half8*)&Bu[b][bo];
      #pragma unroll
      for (int i = 0; i < 4; ++i) {
        accg[c][i] = __builtin_amdgcn_mfma_f32_16x16x32_f16(af[i], bgc, accg[c][i], 0, 0, 0);
        accu[c][i] = __builtin_amdgcn_mfma_f32_16x16x32_f16(af[i], buc, accu[c][i], 0, 0, 0);
      }
    }
  };

  constexpr int NTK = D / BK;   // 32
  stage(0); stage(1);
  for (int k = 0; k < NTK; ++k) {
    if (k + 2 < NTK) {
      stage((k + 2) % 3);
      VMW12();
    } else if (k + 1 < NTK) {
      VMW6();
    } else {
      VMW0();
    }
    __builtin_amdgcn_sched_barrier(0);
    __builtin_amdgcn_s_barrier();
    compute(k % 3);
    __builtin_amdgcn_s_barrier();
  }

  #pragma unroll
  for (int c = 0; c < 4; ++c) {
    int col = n0 + wc * 64 + c * 16 + lrow;
    #pragma unroll
    for (int i = 0; i < 4; ++i) {
      int rowb = row0 + wr * 64 + i * 16 + quad * 4;
      #pragma unroll
      for (int reg = 0; reg < 4; ++reg) {
        float g = accg[c][i][reg], u = accu[c][i][reg];
        Hid[(size_t)(rowb + reg) * M + col] = (_Float16)(g / (1.f + expf(-g)) * u);
      }
    }
  }
}

// ---------------- down grouped GEMM -> per-slot rows Yp ----------------
// 3-buffer counted-vmcnt pipeline (round-7, verified).
__global__ __launch_bounds__(256, 2) void k_down(
    const _Float16* __restrict__ Hid, const _Float16* __restrict__ wdT,
    _Float16* __restrict__ Yp, const int* __restrict__ counts) {
  int lin = blockIdx.x;
  int e = lin & 7;
  int r = lin >> 3;
  int nt = r % NT_DN;
  int mt = r / NT_DN;
  int base_e, pc_e, cnt_e;
  expert_base_pc(counts, e, base_e, pc_e, cnt_e);
  if (mt * TM >= pc_e) return;
  int row0 = base_e + mt * TM;
  int d0 = nt * TN;
  __shared__ _Float16 As[3][TM * BK];   // 3 x 8 KB
  __shared__ _Float16 Bs[3][TN * BK];   // 3 x 8 KB
  int tid = threadIdx.x;
  int w = tid >> 6, lane = tid & 63;
  int lrow = lane & 15, quad = lane >> 4;
  int wr = w >> 1, wc = w & 1;
  int sr = lane >> 2;
  int c4 = lane & 3;
  int swc = ((c4 ^ ((sr >> 1) & 3))) * 8;

  const _Float16* wd_e = wdT + (size_t)e * D * M;
  const _Float16* pA[2]; const _Float16* pB[2];
  int loff[2];
  #pragma unroll
  for (int is = 0; is < 2; ++is) {
    int grow = w * 32 + is * 16 + sr;
    pA[is] = Hid  + (size_t)(row0 + grow) * M + swc;
    pB[is] = wd_e + (size_t)(d0   + grow) * M + swc;
    loff[is] = (w * 2 + is) * 1024;
  }

  int swr = (lrow >> 1) & 3;

  floatx4 acc[4][4] = {};

  auto stage = [&](int b) {
    char* a0 = (char*)&As[b][0];
    char* b0 = (char*)&Bs[b][0];
    #pragma unroll
    for (int is = 0; is < 2; ++is) {
      gl_lds16(pA[is], a0 + loff[is]); pA[is] += BK;
      gl_lds16(pB[is], b0 + loff[is]); pB[is] += BK;
    }
  };
  auto compute = [&](int b) {
    int kc = (quad ^ swr) * 8;
    half8 af[4];
    #pragma unroll
    for (int i = 0; i < 4; ++i)
      af[i] = *(const half8*)&As[b][(wr * 64 + i * 16 + lrow) * BK + kc];
    #pragma unroll
    for (int c = 0; c < 4; ++c) {
      half8 bc = *(const half8*)&Bs[b][(wc * 64 + c * 16 + lrow) * BK + kc];
      #pragma unroll
      for (int i = 0; i < 4; ++i)
        acc[c][i] = __builtin_amdgcn_mfma_f32_16x16x32_f16(af[i], bc, acc[c][i], 0, 0, 0);
    }
  };

  constexpr int NTK = M / BK;   // 44
  stage(0); stage(1);
  for (int k = 0; k < NTK; ++k) {
    if (k + 2 < NTK) {
      stage((k + 2) % 3);
      VMW8();
    } else if (k + 1 < NTK) {
      VMW4();
    } else {
      VMW0();
    }
    __builtin_amdgcn_sched_barrier(0);
    __builtin_amdgcn_s_barrier();
    compute(k % 3);
    __builtin_amdgcn_s_barrier();
  }

  #pragma unroll
  for (int c = 0; c < 4; ++c) {
    int col = d0 + wc * 64 + c * 16 + lrow;
    #pragma unroll
    for (int i = 0; i < 4; ++i) {
      int rowb = row0 + wr * 64 + i * 16 + quad * 4;
      #pragma unroll
      for (int reg = 0; reg < 4; ++reg)
        Yp[(size_t)(rowb + reg) * D + col] = (_Float16)acc[c][i][reg];
    }
  }
}

// ---------------- combine: y[t] = p0*Yp[r0] + p1*Yp[r1] ----------------
__global__ __launch_bounds__(256) void k_combine(
    const _Float16* __restrict__ Yp, const int* __restrict__ counts,
    const int* __restrict__ t2e, const int* __restrict__ t2pos,
    const float* __restrict__ t2p, float* __restrict__ out) {
  int t = blockIdx.x;
  int e0 = t2e[2 * t], e1 = t2e[2 * t + 1];
  int b = 0, b0 = 0, b1 = 0;
  #pragma unroll
  for (int ee = 0; ee < E; ++ee) {
    if (ee == e0) b0 = b;
    if (ee == e1) b1 = b;
    int c = counts[ee * CSTR];
    b += (c + TM - 1) / TM * TM;
  }
  int r0 = b0 + t2pos[2 * t];
  int r1 = b1 + t2pos[2 * t + 1];
  float p0 = t2p[2 * t], p1 = t2p[2 * t + 1];
  int d = threadIdx.x * 4;
  half4 h0 = *(const half4*)(Yp + (size_t)r0 * D + d);
  half4 h1 = *(const half4*)(Yp + (size_t)r1 * D + d);
  float4 o;
  o.x = p0 * (float)h0.x + p1 * (float)h1.x;
  o.y = p0 * (float)h0.y + p1 * (float)h1.y;
  o.z = p0 * (float)h0.z + p1 * (float)h1.z;
  o.w = p0 * (float)h0.w + p1 * (float)h1.w;
  *(float4*)(out + (size_t)t * D + d) = o;
}

// ---------------- launch ----------------
extern "C" void kernel_launch(void* const* d_in, const int* in_sizes, int n_in,
                              void* d_out, int out_size, void* d_ws, size_t ws_size,
                              hipStream_t stream) {
  const float* x     = (const float*)d_in[0];
  const float* wgate = (const float*)d_in[1];
  const float* w_g   = (const float*)d_in[2];
  const float* w_u   = (const float*)d_in[3];
  const float* w_d   = (const float*)d_in[4];
  float* out = (float*)d_out;
  char* ws = (char*)d_ws;

  if (ws_size < WS_NEED) {
    fprintf(stderr, "kernel_launch: ws_size=%zu < needed %zu\n", ws_size, WS_NEED);
    return;
  }

  int* counts = (int*)(ws + OFF_COUNTS);
  int* t2e    = (int*)(ws + OFF_T2E);
  int* t2pos  = (int*)(ws + OFF_T2POS);
  float* t2p  = (float*)(ws + OFF_T2P);
  int* tlist  = (int*)(ws + OFF_TLIST);
  _Float16* Xh  = (_Float16*)(ws + OFF_XG);   // dense f16 tokens; region reused as Yp
  _Float16* Hid = (_Float16*)(ws + OFF_HID);
  _Float16* wgT = (_Float16*)(ws + OFF_WGT);
  _Float16* wuT = (_Float16*)(ws + OFF_WUT);
  _Float16* wdT = (_Float16*)(ws + OFF_WDT);

  hipMemsetAsync(counts, 0, (size_t)E * CSTR * 4, stream);

  k_prep<<<PREP_GRID, 256, 0, stream>>>(x, wgate, w_g, w_u, Xh,
                                        wgT, wuT,
                                        counts, tlist, t2e, t2pos, t2p);
  k_upgate<<<UPG_GRID, 256, 0, stream>>>(Xh, wgT, wuT, Hid, counts, tlist,
                                         w_d, wdT);
  _Float16* Yp = Xh;   // Xh dead after upgate; reuse region as Yp
  k_down<<<E * MT_MAX * NT_DN, 256, 0, stream>>>(Hid, wdT, Yp, counts);
  k_combine<<<T, 256, 0, stream>>>(Yp, counts, t2e, t2pos, t2p, out);
}